// Round 11
// baseline (47649.316 us; speedup 1.0000x reference)
//
#include <hip/hip_runtime.h>
#include <stdint.h>

// Sizes: B=512 S=128 NE=8192 ED=128 DD=32 ND=8 H=512 G=2048 PL=5 IN=160

typedef __attribute__((ext_vector_type(8))) short short8;
typedef __attribute__((ext_vector_type(4))) float f32x4;

__device__ __forceinline__ unsigned short f2bf(float f) {
  union { float f; unsigned u; } v; v.f = f;
  return (unsigned short)((v.u + 0x7fffu + ((v.u >> 16) & 1u)) >> 16);
}
__device__ __forceinline__ float bf2f(unsigned short h) {
  union { unsigned u; float f; } v; v.u = ((unsigned)h) << 16;
  return v.f;
}
__device__ __forceinline__ f32x4 MFMA(short8 a, short8 b, f32x4 c) {
  return __builtin_amdgcn_mfma_f32_16x16x32_bf16(a, b, c, 0, 0, 0);
}

// ---------------- K0: weight bf16 conversions + tables + bias sum ----------
// (xb gather moved: LSTM gathers x directly from linkb/direb — bit-identical
// f2bf bits, tables L2-resident. xb is built only on the fallback path.)
__global__ __launch_bounds__(256) void k_prep(
    const float* __restrict__ link, const float* __restrict__ dire,
    const float* __restrict__ w_ih, const float* __restrict__ w_hh,
    const float* __restrict__ W1, const float* __restrict__ W2,
    const float* __restrict__ W3, const float* __restrict__ b_ih,
    const float* __restrict__ b_hh,
    unsigned short* __restrict__ wihb, unsigned short* __restrict__ whhb,
    unsigned short* __restrict__ w1b, unsigned short* __restrict__ w2b,
    unsigned short* __restrict__ w3b, unsigned short* __restrict__ linkb,
    unsigned short* __restrict__ direb, float* __restrict__ bias_sum)
{
  int64_t e = (int64_t)blockIdx.x * 256 + threadIdx.x;
  if (e < 327680)  { wihb[e] = f2bf(w_ih[e]); return; }
  e -= 327680;
  if (e < 1048576) { whhb[e] = f2bf(w_hh[e]); return; }
  e -= 1048576;
  if (e < 262144)  { w1b[e] = f2bf(W1[e]); return; }
  e -= 262144;
  if (e < 262144)  { w2b[e] = f2bf(W2[e]); return; }
  e -= 262144;
  if (e < 4096)    { w3b[e] = f2bf(W3[e]); return; }
  e -= 4096;
  if (e < 1048704) { linkb[e] = f2bf(link[e]); return; }
  e -= 1048704;
  if (e < 288)     { direb[e] = f2bf(dire[e]); return; }
  e -= 288;
  if (e < 2048)    { bias_sum[e] = b_ih[e] + b_hh[e]; return; }
}

// ---------------- K0b (fallback only): gather xb -----------------------------
__global__ __launch_bounds__(256) void k_prep_xb(
    const int* __restrict__ inputs, const int* __restrict__ dirs,
    const float* __restrict__ link, const float* __restrict__ dire,
    unsigned short* __restrict__ xb)
{
  int ei = blockIdx.x * 256 + threadIdx.x;
  if (ei >= 10485760) return;
  int s = ei / 81920;
  int r = ei % 81920;
  int b = r / 160, k = r % 160;
  float v;
  if (k < 128) v = link[(int64_t)inputs[b*128 + s]*128 + k];
  else         v = dire[dirs[b*128 + s]*32 + (k - 128)];
  xb[ei] = f2bf(v);
}

// ---------------- K1 (fallback only): gates_x = x @ w_ih^T + bias_sum ------
__global__ __launch_bounds__(256) void k_gatesx(
    const unsigned short* __restrict__ xb, const unsigned short* __restrict__ wihb,
    const float* __restrict__ bias_sum, unsigned short* __restrict__ gx)
{
  const int jt1 = blockIdx.x;   // [0,16): 32 hidden units each
  const int bt2 = blockIdx.y;   // [0,2):  256 batch rows each
  const int s   = blockIdx.z;   // [0,128)
  const int t = threadIdx.x, w = t >> 6, l = t & 63;

  __shared__ unsigned short Ash[16*64*8];  // [ms16][l64][8]  16KB
  __shared__ unsigned short Bsh[8*64*8];   // [ns8][l64][8]    8KB

  f32x4 acc[4][8];
#pragma unroll
  for (int ns = 0; ns < 8; ns++) {
    int dj = ns >> 2, g = ns & 3;
    int gcol = 512*g + 32*jt1 + 16*dj + (l & 15);
    float bv = bias_sum[gcol];
    f32x4 b4; b4[0] = bv; b4[1] = bv; b4[2] = bv; b4[3] = bv;
#pragma unroll
    for (int msl = 0; msl < 4; msl++) acc[msl][ns] = b4;
  }
  const unsigned short* xrow = xb + (int64_t)(s*512 + bt2*256)*160;

  for (int ch = 0; ch < 5; ch++) {   // K=160, chunks of 32
    __syncthreads();
#pragma unroll
    for (int i = 0; i < 4; i++) {    // A: 1024 slots of 16B
      int slot = t + 256*i;
      int ms = slot >> 6, ll = slot & 63;
      int row = 16*ms + (ll & 15);
      int k = 32*ch + 8*(ll >> 4);
      *(uint4*)&Ash[slot*8] = *(const uint4*)&xrow[row*160 + k];
    }
#pragma unroll
    for (int i = 0; i < 2; i++) {    // B: 512 slots
      int slot = t + 256*i;
      int ns = slot >> 6, ll = slot & 63;
      int dj = ns >> 2, g = ns & 3;
      int gcol = 512*g + 32*jt1 + 16*dj + (ll & 15);
      int k = 32*ch + 8*(ll >> 4);
      *(uint4*)&Bsh[slot*8] = *(const uint4*)&wihb[gcol*160 + k];
    }
    __syncthreads();
    short8 Bf[8];
#pragma unroll
    for (int ns = 0; ns < 8; ns++) Bf[ns] = *(short8*)&Bsh[(ns*64 + l)*8];
#pragma unroll
    for (int msl = 0; msl < 4; msl++) {
      short8 Af = *(short8*)&Ash[((4*w + msl)*64 + l)*8];
#pragma unroll
      for (int ns = 0; ns < 8; ns++)
        acc[msl][ns] = MFMA(Af, Bf[ns], acc[msl][ns]);
    }
  }
  // epilogue: scatter into step-kernel fragment order (R1 layout)
#pragma unroll
  for (int msl = 0; msl < 4; msl++) {
    int ms1 = 4*w + msl;
    int brow0 = 256*bt2 + 16*ms1;
    int bt = brow0 >> 6;
    int ms2 = (brow0 >> 4) & 3;
    int mw = ms2 >> 1, mt = ms2 & 1;
#pragma unroll
    for (int ns = 0; ns < 8; ns++) {
      int dj = ns >> 2, g = ns & 3;
      int jt2 = 2*jt1 + dj;
      int nw = g >> 1, nt = g & 1;
      int w2 = 2*nw + mw;
      int64_t idx = ((((((int64_t)s*32 + jt2)*8 + bt)*4 + w2)*2 + mt)*2 + nt)*64 + l;
      f32x4 a = acc[msl][ns];
      uint2 pk;
      unsigned short* ps = (unsigned short*)&pk;
      ps[0] = f2bf(a[0]); ps[1] = f2bf(a[1]); ps[2] = f2bf(a[2]); ps[3] = f2bf(a[3]);
      *(uint2*)&gx[idx*4] = pk;
    }
  }
}

// ---------------- K2 (fallback path): one LSTM time step (launched 128x) ----
__global__ __launch_bounds__(256) void k_lstm_step(
    const unsigned short* __restrict__ hprev, unsigned short* __restrict__ hnext,
    float* __restrict__ cbuf, const unsigned short* __restrict__ whhb,
    const unsigned short* __restrict__ gx, int s)
{
  const int jt = blockIdx.x;  // [0,32)
  const int bt = blockIdx.y;  // [0,8)
  const int t = threadIdx.x, w = t >> 6, l = t & 63;
  const int mw = w & 1, nw = w >> 1;

  __shared__ unsigned short Ash[4*2*64*8];  // 8KB
  __shared__ unsigned short Bsh[4*2*64*8];  // 8KB
  __shared__ float gsh[64][68];

  f32x4 acc[2][2];
#pragma unroll
  for (int mt = 0; mt < 2; mt++)
#pragma unroll
  for (int nt = 0; nt < 2; nt++) {
    int64_t idx = ((((((int64_t)s*32 + jt)*8 + bt)*4 + w)*2 + mt)*2 + nt)*64 + l;
    uint2 raw = *(const uint2*)(gx + idx*4);
    const unsigned short* pk = (const unsigned short*)&raw;
    f32x4 v;
    v[0] = bf2f(pk[0]); v[1] = bf2f(pk[1]); v[2] = bf2f(pk[2]); v[3] = bf2f(pk[3]);
    acc[mt][nt] = v;
  }

  for (int ch = 0; ch < 8; ch++) {
    __syncthreads();
#pragma unroll
    for (int i = 0; i < 2; i++) {
      int slot = t + 256*i;
      int p = slot >> 6, ll = slot & 63;
      int ms = p >> 1, ks = p & 1;
      int row = 64*bt + 16*ms + (ll & 15);
      int k = 64*ch + 32*ks + 8*(ll >> 4);
      *(uint4*)&Ash[slot*8] = *(const uint4*)&hprev[row*512 + k];
    }
#pragma unroll
    for (int i = 0; i < 2; i++) {
      int slot = t + 256*i;
      int p = slot >> 6, ll = slot & 63;
      int ns = p >> 1, ks = p & 1;
      int gcol = 512*ns + 16*jt + (ll & 15);
      int k = 64*ch + 32*ks + 8*(ll >> 4);
      *(uint4*)&Bsh[slot*8] = *(const uint4*)&whhb[gcol*512 + k];
    }
    __syncthreads();
#pragma unroll
    for (int ks = 0; ks < 2; ks++) {
      short8 A0 = *(short8*)&Ash[(((2*mw+0)*2 + ks)*64 + l)*8];
      short8 A1 = *(short8*)&Ash[(((2*mw+1)*2 + ks)*64 + l)*8];
      short8 B0 = *(short8*)&Bsh[(((2*nw+0)*2 + ks)*64 + l)*8];
      short8 B1 = *(short8*)&Bsh[(((2*nw+1)*2 + ks)*64 + l)*8];
      acc[0][0] = MFMA(A0, B0, acc[0][0]);
      acc[0][1] = MFMA(A0, B1, acc[0][1]);
      acc[1][0] = MFMA(A1, B0, acc[1][0]);
      acc[1][1] = MFMA(A1, B1, acc[1][1]);
    }
  }

#pragma unroll
  for (int mt = 0; mt < 2; mt++)
#pragma unroll
  for (int nt = 0; nt < 2; nt++) {
    int cb = 32*nw + 16*nt + (l & 15);
    int rb = 32*mw + 16*mt + (l >> 4)*4;
    f32x4 a = acc[mt][nt];
#pragma unroll
    for (int r = 0; r < 4; r++) gsh[rb + r][cb] = a[r];
  }
  __syncthreads();

  {
    int m = t >> 2, u0 = (t & 3)*4;
    int b = 64*bt + m;
    int j0 = 16*jt + u0;
    float* cp = cbuf + b*512 + j0;
    f32x4 c = *(f32x4*)cp;
    f32x4 cn;
    uint2 hv;
    unsigned short* hs = (unsigned short*)&hv;
#pragma unroll
    for (int i2 = 0; i2 < 4; i2++) {
      float gi = gsh[m][ 0 + u0 + i2];
      float gf = gsh[m][16 + u0 + i2];
      float gg = gsh[m][32 + u0 + i2];
      float go = gsh[m][48 + u0 + i2];
      float ii = 1.f/(1.f + expf(-gi));
      float ff = 1.f/(1.f + expf(-gf));
      float g2 = tanhf(gg);
      float oo = 1.f/(1.f + expf(-go));
      float cv = ff*c[i2] + ii*g2;
      cn[i2] = cv;
      hs[i2] = f2bf(oo * tanhf(cv));
    }
    *(f32x4*)cp = cn;
    *(uint2*)&hnext[b*512 + j0] = hv;
  }
}

// ---------------- K2': persistent cooperative LSTM — all 128 steps ---------
// 256 blocks, 1/CU. Verified runtime XCD roster (R9). XCD-LOCAL path:
// h exchange via plain stores (dirty in shared per-XCD L2) + EXPLICIT
// sc0-only inline-asm loads (L1-bypass, L2-HIT, PIPELINED — R10's
// `volatile` was sc0+sc1+serialized: every staging load was a serialized
// L3 round-trip, ~6 us/step). Flags same discipline. AGENT fallback path
// keeps R7 semantics. All spins bounded. x-fragments gathered per step
// from linkb/direb (bit-identical f2bf bits; tables L2-resident) — xb and
// its 21MB HBM stream deleted.
__global__ __launch_bounds__(256, 1) void k_lstm_all(
    unsigned short* __restrict__ hb0, unsigned short* __restrict__ hb1,
    const unsigned short* __restrict__ whhb,
    const unsigned short* __restrict__ wihb,
    const int* __restrict__ inputs, const int* __restrict__ dirs,
    const unsigned short* __restrict__ linkb,
    const unsigned short* __restrict__ direb,
    const float* __restrict__ bias_sum,
    unsigned int* __restrict__ flags,        // [8 groups][64 u32 stride]
    unsigned int* __restrict__ cnt)          // [0..7] per-XCD, [8] total
{
  const int t = threadIdx.x, w = t >> 6, l = t & 63;
  const int mw = w & 1, nw = w >> 1;

  __shared__ unsigned short Ash[8*2*4*64*8]; // 64KB
  __shared__ float gsh[64][68];              // 17.4KB
  __shared__ int roster[3];                  // jt, bt, loc

  if (t == 0) {
    unsigned xcd;
    asm volatile("s_getreg_b32 %0, hwreg(HW_REG_XCC_ID)" : "=s"(xcd));
    xcd &= 7u;
    unsigned slot = __hip_atomic_fetch_add(&cnt[xcd], 1u, __ATOMIC_RELAXED,
                                           __HIP_MEMORY_SCOPE_AGENT);
    __hip_atomic_fetch_add(&cnt[8], 1u, __ATOMIC_RELEASE,
                           __HIP_MEMORY_SCOPE_AGENT);
    bool ok = true;
    for (int it2 = 0; ; ++it2) {             // one-time grid barrier, bounded
      if (__hip_atomic_load(&cnt[8], __ATOMIC_ACQUIRE,
                            __HIP_MEMORY_SCOPE_AGENT) >= 256u) break;
      if (it2 > 5000000) { ok = false; break; }
      __builtin_amdgcn_s_sleep(2);
    }
    bool uniform = ok;
    for (int x2 = 0; x2 < 8; x2++)
      if (__hip_atomic_load(&cnt[x2], __ATOMIC_RELAXED,
                            __HIP_MEMORY_SCOPE_AGENT) != 32u) uniform = false;
    if (uniform) { roster[0] = (int)slot; roster[1] = (int)xcd; roster[2] = 1; }
    else { roster[0] = (int)(blockIdx.x & 31); roster[1] = (int)(blockIdx.x >> 5);
           roster[2] = 0; }
  }
  __syncthreads();
  const int jt  = roster[0];   // [0,32) unit tile
  const int bt  = roster[1];   // [0,8)  batch group
  const bool loc = roster[2] != 0;

  unsigned int* gf = flags + bt*64;          // 256B stride per group

  // ---- hoist w_hh fragments into registers (once) ----
  short8 Bw[8][2][2];                        // 128 VGPRs
#pragma unroll
  for (int ch = 0; ch < 8; ch++)
#pragma unroll
  for (int ks = 0; ks < 2; ks++)
#pragma unroll
  for (int nsl = 0; nsl < 2; nsl++) {
    int ns = 2*nw + nsl;
    int gcol = 512*ns + 16*jt + (l & 15);
    int k = 64*ch + 32*ks + 8*(l >> 4);
    Bw[ch][ks][nsl] = *(const short8*)&whhb[(int64_t)gcol*512 + k];
  }
  // ---- hoist w_ih fragments (K=160: 5 chunks of 32) ----
  short8 Wx[5][2];                           // 40 VGPRs
#pragma unroll
  for (int ch = 0; ch < 5; ch++)
#pragma unroll
  for (int nsl = 0; nsl < 2; nsl++) {
    int ns = 2*nw + nsl;
    int gcol = 512*ns + 16*jt + (l & 15);
    int k = 32*ch + 8*(l >> 4);
    Wx[ch][nsl] = *(const short8*)&wihb[(int64_t)gcol*160 + k];
  }
  // ---- bias for this thread's two gate columns ----
  float bias_b[2];
#pragma unroll
  for (int nt = 0; nt < 2; nt++) {
    int g = 2*nw + nt;
    bias_b[nt] = bias_sum[512*g + 16*jt + (l & 15)];
  }

  float creg[4] = {0.f, 0.f, 0.f, 0.f};
  const int m = t >> 2, u0 = (t & 3)*4;
  const int bgl = 64*bt + m;
  const int j0 = 16*jt + u0;
  const int kk8 = 8*(l >> 4);
  const int row0 = 64*bt + 32*mw + (l & 15);   // mt=0 batch row
  const int row1 = row0 + 16;                  // mt=1 batch row
  int bad = 0;                               // wave-0 poll timeout latch

  // prologue: x fragments for step 0 (gathered; bit-identical to xb path)
  short8 xf[2][5];                           // 40 VGPRs
  {
    int i0 = inputs[row0*128 + 0], i1 = inputs[row1*128 + 0];
    int d0 = dirs[row0*128 + 0],  d1 = dirs[row1*128 + 0];
#pragma unroll
    for (int ch = 0; ch < 4; ch++) {
      xf[0][ch] = *(const short8*)&linkb[(int64_t)i0*128 + 32*ch + kk8];
      xf[1][ch] = *(const short8*)&linkb[(int64_t)i1*128 + 32*ch + kk8];
    }
    xf[0][4] = *(const short8*)&direb[d0*32 + kk8];
    xf[1][4] = *(const short8*)&direb[d1*32 + kk8];
  }

  for (int s = 0; s < 128; s++) {
    const unsigned short* hp = (s & 1) ? hb1 : hb0;
    unsigned short* hn = (s & 1) ? hb0 : hb1;

    // ---- x-gates for step s (bit-exact with k_gatesx; no h dependency) ----
    uint2 gxr[2][2];
#pragma unroll
    for (int mt = 0; mt < 2; mt++)
#pragma unroll
    for (int nt = 0; nt < 2; nt++) {
      f32x4 a;
      a[0] = bias_b[nt]; a[1] = bias_b[nt]; a[2] = bias_b[nt]; a[3] = bias_b[nt];
#pragma unroll
      for (int ch = 0; ch < 5; ch++)
        a = MFMA(xf[mt][ch], Wx[ch][nt], a);
      unsigned short* ps = (unsigned short*)&gxr[mt][nt];
      ps[0] = f2bf(a[0]); ps[1] = f2bf(a[1]); ps[2] = f2bf(a[2]); ps[3] = f2bf(a[3]);
    }

    // ---- prefetch x fragments for step s+1 (plain cached gathers; tables
    // are read-only and L2-resident) ----
    {
      int sn = (s + 1 < 128) ? s + 1 : 127;
      int i0 = inputs[row0*128 + sn], i1 = inputs[row1*128 + sn];
      int d0 = dirs[row0*128 + sn],  d1 = dirs[row1*128 + sn];
#pragma unroll
      for (int ch = 0; ch < 4; ch++) {
        xf[0][ch] = *(const short8*)&linkb[(int64_t)i0*128 + 32*ch + kk8];
        xf[1][ch] = *(const short8*)&linkb[(int64_t)i1*128 + 32*ch + kk8];
      }
      xf[0][4] = *(const short8*)&direb[d0*32 + kk8];
      xf[1][4] = *(const short8*)&direb[d1*32 + kk8];
    }

    // ---- wait: all 32 group flags >= s (wave 0 polls; BOUNDED) ----
    if (s > 0) {
      if (w == 0 && !bad) {
        unsigned tgt = (unsigned)s;
        for (int it2 = 0; ; ++it2) {
          unsigned v;
          if (loc) {
            // sc0-only: bypass L1, read this XCD's L2 (where plain-stored
            // flags live); agent atomics would read L3 and never see them.
            asm volatile("global_load_dword %0, %1, off sc0"
                         : "=v"(v) : "v"(&gf[l & 31]) : "memory");
            asm volatile("s_waitcnt vmcnt(0)" ::: "memory");
          } else {
            v = __hip_atomic_load(&gf[l & 31], __ATOMIC_RELAXED,
                                  __HIP_MEMORY_SCOPE_AGENT);
          }
          if (__all((int)(v >= tgt))) break;
          if (it2 > 1000000) { bad = 1; break; }   // terminate, don't hang
          __builtin_amdgcn_s_sleep(1);
        }
      }
      __syncthreads();
    }

    // ---- stage A tile (64 rows x K=512) -> LDS ----
    if (loc) {
      // sc0-only pipelined loads: issue all 16, ONE waitcnt, then LDS writes
      uint4 tmp[16];
#pragma unroll
      for (int i = 0; i < 16; i++) {
        int p = w*16 + i;                    // = ch*8 + ks*4 + ms
        int ms = p & 3, ks = (p >> 2) & 1, ch = p >> 3;
        int row = 64*bt + 16*ms + (l & 15);
        int k = 64*ch + 32*ks + 8*(l >> 4);
        const unsigned short* src = hp + (int64_t)row*512 + k;
        asm volatile("global_load_dwordx4 %0, %1, off sc0"
                     : "=v"(tmp[i]) : "v"(src) : "memory");
      }
      asm volatile("s_waitcnt vmcnt(0)" ::: "memory");
      __builtin_amdgcn_sched_barrier(0);
#pragma unroll
      for (int i = 0; i < 16; i++) {
        int p = w*16 + i;
        *(uint4*)&Ash[(p*64 + l)*8] = tmp[i];
      }
    } else {
      // agent-scope loads from the L3 coherence point (R7-proven)
#pragma unroll
      for (int i = 0; i < 16; i++) {
        int p = w*16 + i;
        int ms = p & 3, ks = (p >> 2) & 1, ch = p >> 3;
        int row = 64*bt + 16*ms + (l & 15);
        int k = 64*ch + 32*ks + 8*(l >> 4);
        const unsigned long long* src =
            (const unsigned long long*)(hp + (int64_t)row*512 + k);
        unsigned long long d0 = __hip_atomic_load(src,     __ATOMIC_RELAXED,
                                                  __HIP_MEMORY_SCOPE_AGENT);
        unsigned long long d1 = __hip_atomic_load(src + 1, __ATOMIC_RELAXED,
                                                  __HIP_MEMORY_SCOPE_AGENT);
        unsigned long long tmp2[2] = {d0, d1};
        *(uint4*)&Ash[(p*64 + l)*8] = *(const uint4*)tmp2;
      }
    }
    __syncthreads();

    f32x4 acc[2][2];
#pragma unroll
    for (int mt = 0; mt < 2; mt++)
#pragma unroll
    for (int nt = 0; nt < 2; nt++) {
      const unsigned short* pk = (const unsigned short*)&gxr[mt][nt];
      f32x4 v;
      v[0] = bf2f(pk[0]); v[1] = bf2f(pk[1]); v[2] = bf2f(pk[2]); v[3] = bf2f(pk[3]);
      acc[mt][nt] = v;
    }

#pragma unroll
    for (int ch = 0; ch < 8; ch++)
#pragma unroll
    for (int ks = 0; ks < 2; ks++) {
      short8 A0 = *(short8*)&Ash[((ch*8 + ks*4 + 2*mw + 0)*64 + l)*8];
      short8 A1 = *(short8*)&Ash[((ch*8 + ks*4 + 2*mw + 1)*64 + l)*8];
      acc[0][0] = MFMA(A0, Bw[ch][ks][0], acc[0][0]);
      acc[0][1] = MFMA(A0, Bw[ch][ks][1], acc[0][1]);
      acc[1][0] = MFMA(A1, Bw[ch][ks][0], acc[1][0]);
      acc[1][1] = MFMA(A1, Bw[ch][ks][1], acc[1][1]);
    }

    // gate exchange
#pragma unroll
    for (int mt = 0; mt < 2; mt++)
#pragma unroll
    for (int nt = 0; nt < 2; nt++) {
      int cb = 32*nw + 16*nt + (l & 15);
      int rb = 32*mw + 16*mt + (l >> 4)*4;
      f32x4 a = acc[mt][nt];
#pragma unroll
      for (int r = 0; r < 4; r++) gsh[rb + r][cb] = a[r];
    }
    __syncthreads();

    {
      union { unsigned short hs[4]; unsigned long long v; } hv;
#pragma unroll
      for (int i2 = 0; i2 < 4; i2++) {
        float gi = gsh[m][ 0 + u0 + i2];
        float gf2 = gsh[m][16 + u0 + i2];
        float gg = gsh[m][32 + u0 + i2];
        float go = gsh[m][48 + u0 + i2];
        float ii = 1.f/(1.f + expf(-gi));
        float ff = 1.f/(1.f + expf(-gf2));
        float g2 = tanhf(gg);
        float oo = 1.f/(1.f + expf(-go));
        float cv = ff*creg[i2] + ii*g2;
        creg[i2] = cv;
        hv.hs[i2] = f2bf(oo * tanhf(cv));
      }
      if (loc)   // plain store: dirty line in this XCD's L2 (exchange point)
        *(unsigned long long*)&hn[(int64_t)bgl*512 + j0] = hv.v;
      else       // agent store: write-through to the L3 coherence point
        __hip_atomic_store((unsigned long long*)&hn[(int64_t)bgl*512 + j0],
                           hv.v, __ATOMIC_RELAXED, __HIP_MEMORY_SCOPE_AGENT);
    }

    // __syncthreads drains vmcnt(0) in every wave (h stores ACKed at the
    // exchange point) BEFORE the flag post -> release without any fence.
    __syncthreads();
    if (t == 0) {
      asm volatile("s_waitcnt vmcnt(0)" ::: "memory");  // belt-and-braces
      if (loc) *(volatile unsigned*)&gf[jt] = (unsigned)(s + 1);
      else __hip_atomic_store(&gf[jt], (unsigned)(s + 1), __ATOMIC_RELAXED,
                              __HIP_MEMORY_SCOPE_AGENT);
    }
  }
}

// ---------------- generic bf16 GEMM: C = act(A(MxK) * B(NxK)^T + bias) -----
// MODE 0: bf16 out + bias + relu;  MODE 1: f32 out + bias, cols < nreal;
// MODE 2: f32 out replicated x5 (pred_hard), row stride 40960.
template<int MODE>
__global__ __launch_bounds__(256) void k_gemm(
    const unsigned short* __restrict__ A, int lda,
    const unsigned short* __restrict__ Bm, int ldb, int nreal,
    const float* __restrict__ bias,
    void* __restrict__ outp, int ldo, int nchunks)
{
  const int bX = blockIdx.x, bY = blockIdx.y;
  const int t = threadIdx.x, w = t >> 6, l = t & 63;
  const int mw = w & 1, nw = w >> 1;
  __shared__ unsigned short Ash[4*2*64*8];
  __shared__ unsigned short Bsh[4*2*64*8];

  f32x4 acc[2][2];
  f32x4 z; z[0] = 0.f; z[1] = 0.f; z[2] = 0.f; z[3] = 0.f;
  acc[0][0] = z; acc[0][1] = z; acc[1][0] = z; acc[1][1] = z;

  for (int ch = 0; ch < nchunks; ch++) {
    __syncthreads();
#pragma unroll
    for (int i = 0; i < 2; i++) {
      int slot = t + 256*i;
      int p = slot >> 6, ll = slot & 63;
      int ms = p >> 1, ks = p & 1;
      int row = 64*bY + 16*ms + (ll & 15);
      int k = 64*ch + 32*ks + 8*(ll >> 4);
      *(uint4*)&Ash[slot*8] = *(const uint4*)&A[(int64_t)row*lda + k];
    }
#pragma unroll
    for (int i = 0; i < 2; i++) {
      int slot = t + 256*i;
      int p = slot >> 6, ll = slot & 63;
      int ns = p >> 1, ks = p & 1;
      int row = 64*bX + 16*ns + (ll & 15);
      if (row >= nreal) row = nreal - 1;   // clamp (garbage cols masked later)
      int k = 64*ch + 32*ks + 8*(ll >> 4);
      *(uint4*)&Bsh[slot*8] = *(const uint4*)&Bm[(int64_t)row*ldb + k];
    }
    __syncthreads();
#pragma unroll
    for (int ks = 0; ks < 2; ks++) {
      short8 A0 = *(short8*)&Ash[(((2*mw+0)*2 + ks)*64 + l)*8];
      short8 A1 = *(short8*)&Ash[(((2*mw+1)*2 + ks)*64 + l)*8];
      short8 B0 = *(short8*)&Bsh[(((2*nw+0)*2 + ks)*64 + l)*8];
      short8 B1 = *(short8*)&Bsh[(((2*nw+1)*2 + ks)*64 + l)*8];
      acc[0][0] = MFMA(A0, B0, acc[0][0]);
      acc[0][1] = MFMA(A0, B1, acc[0][1]);
      acc[1][0] = MFMA(A1, B0, acc[1][0]);
      acc[1][1] = MFMA(A1, B1, acc[1][1]);
    }
  }

#pragma unroll
  for (int mt = 0; mt < 2; mt++)
#pragma unroll
  for (int nt = 0; nt < 2; nt++) {
    int n = 64*bX + 32*nw + 16*nt + (l & 15);
    int rb = 64*bY + 32*mw + 16*mt + (l >> 4)*4;
    f32x4 a = acc[mt][nt];
    if (MODE == 0) {
      float bv = bias[n];
#pragma unroll
      for (int r = 0; r < 4; r++) {
        float v = a[r] + bv; v = v > 0.f ? v : 0.f;
        ((unsigned short*)outp)[(int64_t)(rb + r)*ldo + n] = f2bf(v);
      }
    } else if (MODE == 1) {
      if (n < nreal) {
        float bv = bias[n];
#pragma unroll
        for (int r = 0; r < 4; r++)
          ((float*)outp)[(int64_t)(rb + r)*ldo + n] = a[r] + bv;
      }
    } else {
#pragma unroll
      for (int r = 0; r < 4; r++) {
        float v = a[r];
        float* o = (float*)outp + (int64_t)(rb + r)*40960 + n;
#pragma unroll
        for (int p5 = 0; p5 < 5; p5++) o[p5*8192] = v;
      }
    }
  }
}

// ---------------- K4: softmax head, top-2, loss, count, query, pdr copy ----
__global__ __launch_bounds__(256) void k_head(
    const float* __restrict__ logits, const int* __restrict__ inputs,
    const int* __restrict__ goal, const int* __restrict__ ldm,
    const float* __restrict__ link, const float* __restrict__ dire,
    const float* __restrict__ pdr, unsigned short* __restrict__ qb,
    float* __restrict__ out)
{
  const int blk = blockIdx.x, t = threadIdx.x;
  __shared__ int idxsh[64][2];
  __shared__ float redf[256];
  __shared__ int redi[256];

  if (t < 64) {                       // top-2 for this block's 64 rows
    int b = 64*blk + t;
    float v[8];
#pragma unroll
    for (int i = 0; i < 8; i++) v[i] = logits[b*8 + i];
    int i0 = 0; float m0 = v[0];
#pragma unroll
    for (int i = 1; i < 8; i++) if (v[i] > m0) { m0 = v[i]; i0 = i; }
    int i1 = -1; float m1 = -3.4e38f;
#pragma unroll
    for (int i = 0; i < 8; i++) if (i != i0 && v[i] > m1) { m1 = v[i]; i1 = i; }
    idxsh[t][0] = i0; idxsh[t][1] = i1;
  }
  __syncthreads();
  {                                   // query = le + pad(0.5*(de0+de1)) (bf16)
    int rl = t >> 2, kc = (t & 3) * 32;
    int b = 64*blk + rl;
    int last = inputs[b*128 + 127];
    const float* le = link + (int64_t)last*128 + kc;
    int i0 = idxsh[rl][0], i1 = idxsh[rl][1];
    unsigned short q[32] __attribute__((aligned(16)));
#pragma unroll
    for (int k = 0; k < 32; k++) {
      float v = le[k];
      if (kc == 0) v += 0.5f*(dire[(i0+1)*32 + k] + dire[(i1+1)*32 + k]);
      q[k] = f2bf(v);
    }
    uint4* dst = (uint4*)&qb[b*128 + kc];
#pragma unroll
    for (int x = 0; x < 4; x++) dst[x] = ((uint4*)q)[x];
  }
  if (blk == 0) {                     // loss + direction_correct over all rows
    float lsum = 0.f; int csum = 0;
    for (int rr = t; rr < 512; rr += 256) {
      float v[8];
#pragma unroll
      for (int i = 0; i < 8; i++) v[i] = logits[rr*8 + i];
      float mx = v[0];
#pragma unroll
      for (int i = 1; i < 8; i++) mx = v[i] > mx ? v[i] : mx;
      float se = 0.f;
#pragma unroll
      for (int i = 0; i < 8; i++) se += expf(v[i] - mx);
      float lse = logf(se);
      int last = inputs[rr*128 + 127];
      int lbl = ldm[(int64_t)(last - 1)*8192 + goal[rr]];
      lsum += v[lbl] - mx - lse;      // ls2 == log_softmax (idempotent)
      int i0 = 0; float m0 = v[0];
#pragma unroll
      for (int i = 1; i < 8; i++) if (v[i] > m0) { m0 = v[i]; i0 = i; }
      int i1 = -1; float m1 = -3.4e38f;
#pragma unroll
      for (int i = 0; i < 8; i++) if (i != i0 && v[i] > m1) { m1 = v[i]; i1 = i; }
      if (i0 == lbl || i1 == lbl) csum++;
    }
    redf[t] = lsum; redi[t] = csum;
    __syncthreads();
    for (int o2 = 128; o2 > 0; o2 >>= 1) {
      if (t < o2) { redf[t] += redf[t + o2]; redi[t] += redi[t + o2]; }
      __syncthreads();
    }
    if (t == 0) {
      out[20992000] = -redf[0] / 512.f * 5.f;
      out[20992001] = (float)redi[0];
    }
  }
  for (int i = 0; i < 10; i++) {      // pred_d_rand passthrough
    int idx = blk*2560 + t*10 + i;
    out[20971520 + idx] = pdr[idx];
  }
}

// ---------------- host ----------------
extern "C" void kernel_launch(void* const* d_in, const int* in_sizes, int n_in,
                              void* d_out, int out_size, void* d_ws, size_t ws_size,
                              hipStream_t stream)
{
  const int* inputs = (const int*)d_in[0];
  const int* dirs   = (const int*)d_in[1];
  const int* goal   = (const int*)d_in[2];
  const int* ldm    = (const int*)d_in[3];
  const float* pdr  = (const float*)d_in[4];
  const float* link = (const float*)d_in[5];
  const float* dire = (const float*)d_in[6];
  const float* w_ih = (const float*)d_in[7];
  const float* b_ih = (const float*)d_in[8];
  const float* w_hh = (const float*)d_in[9];
  const float* b_hh = (const float*)d_in[10];
  const float* W1   = (const float*)d_in[11];
  const float* b1   = (const float*)d_in[12];
  const float* W2   = (const float*)d_in[13];
  const float* b2   = (const float*)d_in[14];
  const float* W3   = (const float*)d_in[15];
  const float* b3   = (const float*)d_in[16];
  float* out = (float*)d_out;

  char* wsp = (char*)d_ws;
  size_t off = 0;
  auto alloc = [&](size_t bytes) { char* p = wsp + off; off += (bytes + 255) & ~(size_t)255; return p; };
  unsigned short* xb    = (unsigned short*)alloc(10485760ull*2);  // fallback only
  unsigned short* wihb  = (unsigned short*)alloc(327680ull*2);
  unsigned short* whhb  = (unsigned short*)alloc(1048576ull*2);
  unsigned short* w1b   = (unsigned short*)alloc(262144ull*2);
  unsigned short* w2b   = (unsigned short*)alloc(262144ull*2);
  unsigned short* w3b   = (unsigned short*)alloc(4096ull*2);
  unsigned short* linkb = (unsigned short*)alloc(1048704ull*2);
  unsigned short* direb = (unsigned short*)alloc(288ull*2);
  float* bias_sum       = (float*)alloc(2048ull*4);
  unsigned short* gxb   = (unsigned short*)alloc(134217728ull*2);  // fallback only
  unsigned short* hb0   = (unsigned short*)alloc(262144ull*2);
  unsigned short* hb1   = (unsigned short*)alloc(262144ull*2);
  float* cbuf           = (float*)alloc(262144ull*4);
  unsigned short* z1b   = (unsigned short*)alloc(262144ull*2);
  unsigned short* z2b   = (unsigned short*)alloc(262144ull*2);
  float* logits         = (float*)alloc(4096ull*4);
  unsigned short* qb    = (unsigned short*)alloc(65536ull*2);
  unsigned int* flags   = (unsigned int*)alloc(4096);   // 8x64 u32 (256B/grp)
  unsigned int* cnt     = (unsigned int*)alloc(256);    // roster counters

  hipMemsetAsync(hb0, 0, 262144ull*2, stream);    // h0 = 0 (bf16 zeros)
  hipMemsetAsync(flags, 0, 4096, stream);         // flags = 0
  hipMemsetAsync(cnt, 0, 256, stream);            // roster counters = 0

  k_prep<<<11546, 256, 0, stream>>>(link, dire, w_ih, w_hh, W1, W2, W3,
                                    b_ih, b_hh, wihb, whhb, w1b, w2b, w3b,
                                    linkb, direb, bias_sum);

  {
    unsigned short* a0 = hb0; unsigned short* a1 = hb1;
    const unsigned short* a2 = whhb; const unsigned short* a3 = wihb;
    const int* a4 = inputs; const int* a5 = dirs;
    const unsigned short* a6 = linkb; const unsigned short* a7 = direb;
    const float* a8 = bias_sum;
    unsigned int* a9 = flags; unsigned int* a10 = cnt;
    void* kargs[11] = { &a0, &a1, &a2, &a3, &a4, &a5, &a6, &a7, &a8, &a9, &a10 };
    hipError_t ce = hipLaunchCooperativeKernel((const void*)k_lstm_all,
                                               dim3(256,1,1), dim3(256,1,1),
                                               kargs, 0, stream);
    if (ce != hipSuccess) {
      // fallback: materialize xb + gx then per-step launches (verified path)
      k_prep_xb<<<40960, 256, 0, stream>>>(inputs, dirs, link, dire, xb);
      k_gatesx<<<dim3(16,2,128), 256, 0, stream>>>(xb, wihb, bias_sum, gxb);
      hipMemsetAsync(cbuf, 0, 262144ull*4, stream);
      for (int s = 0; s < 128; s++) {
        const unsigned short* hp = (s & 1) ? hb1 : hb0;
        unsigned short* hn = (s & 1) ? hb0 : hb1;
        k_lstm_step<<<dim3(32,8), 256, 0, stream>>>(hp, hn, cbuf, whhb, gxb, s);
      }
    }
  }
  // final h in hb0 (128 steps, even)
  k_gemm<0><<<dim3(8,8), 256, 0, stream>>>(hb0, 512, w1b, 512, 512, b1, z1b, 512, 8);
  k_gemm<0><<<dim3(8,8), 256, 0, stream>>>(z1b, 512, w2b, 512, 512, b2, z2b, 512, 8);
  k_gemm<1><<<dim3(1,8), 256, 0, stream>>>(z2b, 512, w3b, 512, 8, b3, logits, 8, 8);
  k_head<<<8, 256, 0, stream>>>(logits, inputs, goal, ldm, link, dire, pdr, qb, out);
  k_gemm<2><<<dim3(128,8), 256, 0, stream>>>(qb, 128, linkb + 128, 128, 8192, nullptr, out, 0, 2);
}

// Round 12
// 1316.811 us; speedup vs baseline: 36.1854x; 36.1854x over previous
//
#include <hip/hip_runtime.h>
#include <stdint.h>

// Sizes: B=512 S=128 NE=8192 ED=128 DD=32 ND=8 H=512 G=2048 PL=5 IN=160

typedef __attribute__((ext_vector_type(8))) short short8;
typedef __attribute__((ext_vector_type(4))) float f32x4;

__device__ __forceinline__ unsigned short f2bf(float f) {
  union { float f; unsigned u; } v; v.f = f;
  return (unsigned short)((v.u + 0x7fffu + ((v.u >> 16) & 1u)) >> 16);
}
__device__ __forceinline__ float bf2f(unsigned short h) {
  union { unsigned u; float f; } v; v.u = ((unsigned)h) << 16;
  return v.f;
}
__device__ __forceinline__ f32x4 MFMA(short8 a, short8 b, f32x4 c) {
  return __builtin_amdgcn_mfma_f32_16x16x32_bf16(a, b, c, 0, 0, 0);
}

// ---------------- K0: weight bf16 conversions + tables + bias sum ----------
__global__ __launch_bounds__(256) void k_prep(
    const float* __restrict__ link, const float* __restrict__ dire,
    const float* __restrict__ w_ih, const float* __restrict__ w_hh,
    const float* __restrict__ W1, const float* __restrict__ W2,
    const float* __restrict__ W3, const float* __restrict__ b_ih,
    const float* __restrict__ b_hh,
    unsigned short* __restrict__ wihb, unsigned short* __restrict__ whhb,
    unsigned short* __restrict__ w1b, unsigned short* __restrict__ w2b,
    unsigned short* __restrict__ w3b, unsigned short* __restrict__ linkb,
    unsigned short* __restrict__ direb, float* __restrict__ bias_sum)
{
  int64_t e = (int64_t)blockIdx.x * 256 + threadIdx.x;
  if (e < 327680)  { wihb[e] = f2bf(w_ih[e]); return; }
  e -= 327680;
  if (e < 1048576) { whhb[e] = f2bf(w_hh[e]); return; }
  e -= 1048576;
  if (e < 262144)  { w1b[e] = f2bf(W1[e]); return; }
  e -= 262144;
  if (e < 262144)  { w2b[e] = f2bf(W2[e]); return; }
  e -= 262144;
  if (e < 4096)    { w3b[e] = f2bf(W3[e]); return; }
  e -= 4096;
  if (e < 1048704) { linkb[e] = f2bf(link[e]); return; }
  e -= 1048704;
  if (e < 288)     { direb[e] = f2bf(dire[e]); return; }
  e -= 288;
  if (e < 2048)    { bias_sum[e] = b_ih[e] + b_hh[e]; return; }
}

// ---------------- K0b (fallback only): gather xb -----------------------------
__global__ __launch_bounds__(256) void k_prep_xb(
    const int* __restrict__ inputs, const int* __restrict__ dirs,
    const float* __restrict__ link, const float* __restrict__ dire,
    unsigned short* __restrict__ xb)
{
  int ei = blockIdx.x * 256 + threadIdx.x;
  if (ei >= 10485760) return;
  int s = ei / 81920;
  int r = ei % 81920;
  int b = r / 160, k = r % 160;
  float v;
  if (k < 128) v = link[(int64_t)inputs[b*128 + s]*128 + k];
  else         v = dire[dirs[b*128 + s]*32 + (k - 128)];
  xb[ei] = f2bf(v);
}

// ---------------- K1 (fallback only): gates_x = x @ w_ih^T + bias_sum ------
__global__ __launch_bounds__(256) void k_gatesx(
    const unsigned short* __restrict__ xb, const unsigned short* __restrict__ wihb,
    const float* __restrict__ bias_sum, unsigned short* __restrict__ gx)
{
  const int jt1 = blockIdx.x;   // [0,16): 32 hidden units each
  const int bt2 = blockIdx.y;   // [0,2):  256 batch rows each
  const int s   = blockIdx.z;   // [0,128)
  const int t = threadIdx.x, w = t >> 6, l = t & 63;

  __shared__ unsigned short Ash[16*64*8];  // [ms16][l64][8]  16KB
  __shared__ unsigned short Bsh[8*64*8];   // [ns8][l64][8]    8KB

  f32x4 acc[4][8];
#pragma unroll
  for (int ns = 0; ns < 8; ns++) {
    int dj = ns >> 2, g = ns & 3;
    int gcol = 512*g + 32*jt1 + 16*dj + (l & 15);
    float bv = bias_sum[gcol];
    f32x4 b4; b4[0] = bv; b4[1] = bv; b4[2] = bv; b4[3] = bv;
#pragma unroll
    for (int msl = 0; msl < 4; msl++) acc[msl][ns] = b4;
  }
  const unsigned short* xrow = xb + (int64_t)(s*512 + bt2*256)*160;

  for (int ch = 0; ch < 5; ch++) {   // K=160, chunks of 32
    __syncthreads();
#pragma unroll
    for (int i = 0; i < 4; i++) {    // A: 1024 slots of 16B
      int slot = t + 256*i;
      int ms = slot >> 6, ll = slot & 63;
      int row = 16*ms + (ll & 15);
      int k = 32*ch + 8*(ll >> 4);
      *(uint4*)&Ash[slot*8] = *(const uint4*)&xrow[row*160 + k];
    }
#pragma unroll
    for (int i = 0; i < 2; i++) {    // B: 512 slots
      int slot = t + 256*i;
      int ns = slot >> 6, ll = slot & 63;
      int dj = ns >> 2, g = ns & 3;
      int gcol = 512*g + 32*jt1 + 16*dj + (ll & 15);
      int k = 32*ch + 8*(ll >> 4);
      *(uint4*)&Bsh[slot*8] = *(const uint4*)&wihb[gcol*160 + k];
    }
    __syncthreads();
    short8 Bf[8];
#pragma unroll
    for (int ns = 0; ns < 8; ns++) Bf[ns] = *(short8*)&Bsh[(ns*64 + l)*8];
#pragma unroll
    for (int msl = 0; msl < 4; msl++) {
      short8 Af = *(short8*)&Ash[((4*w + msl)*64 + l)*8];
#pragma unroll
      for (int ns = 0; ns < 8; ns++)
        acc[msl][ns] = MFMA(Af, Bf[ns], acc[msl][ns]);
    }
  }
  // epilogue: scatter into step-kernel fragment order (R1 layout)
#pragma unroll
  for (int msl = 0; msl < 4; msl++) {
    int ms1 = 4*w + msl;
    int brow0 = 256*bt2 + 16*ms1;
    int bt = brow0 >> 6;
    int ms2 = (brow0 >> 4) & 3;
    int mw = ms2 >> 1, mt = ms2 & 1;
#pragma unroll
    for (int ns = 0; ns < 8; ns++) {
      int dj = ns >> 2, g = ns & 3;
      int jt2 = 2*jt1 + dj;
      int nw = g >> 1, nt = g & 1;
      int w2 = 2*nw + mw;
      int64_t idx = ((((((int64_t)s*32 + jt2)*8 + bt)*4 + w2)*2 + mt)*2 + nt)*64 + l;
      f32x4 a = acc[msl][ns];
      uint2 pk;
      unsigned short* ps = (unsigned short*)&pk;
      ps[0] = f2bf(a[0]); ps[1] = f2bf(a[1]); ps[2] = f2bf(a[2]); ps[3] = f2bf(a[3]);
      *(uint2*)&gx[idx*4] = pk;
    }
  }
}

// ---------------- K2 (fallback path): one LSTM time step (launched 128x) ----
__global__ __launch_bounds__(256) void k_lstm_step(
    const unsigned short* __restrict__ hprev, unsigned short* __restrict__ hnext,
    float* __restrict__ cbuf, const unsigned short* __restrict__ whhb,
    const unsigned short* __restrict__ gx, int s)
{
  const int jt = blockIdx.x;  // [0,32)
  const int bt = blockIdx.y;  // [0,8)
  const int t = threadIdx.x, w = t >> 6, l = t & 63;
  const int mw = w & 1, nw = w >> 1;

  __shared__ unsigned short Ash[4*2*64*8];  // 8KB
  __shared__ unsigned short Bsh[4*2*64*8];  // 8KB
  __shared__ float gsh[64][68];

  f32x4 acc[2][2];
#pragma unroll
  for (int mt = 0; mt < 2; mt++)
#pragma unroll
  for (int nt = 0; nt < 2; nt++) {
    int64_t idx = ((((((int64_t)s*32 + jt)*8 + bt)*4 + w)*2 + mt)*2 + nt)*64 + l;
    uint2 raw = *(const uint2*)(gx + idx*4);
    const unsigned short* pk = (const unsigned short*)&raw;
    f32x4 v;
    v[0] = bf2f(pk[0]); v[1] = bf2f(pk[1]); v[2] = bf2f(pk[2]); v[3] = bf2f(pk[3]);
    acc[mt][nt] = v;
  }

  for (int ch = 0; ch < 8; ch++) {
    __syncthreads();
#pragma unroll
    for (int i = 0; i < 2; i++) {
      int slot = t + 256*i;
      int p = slot >> 6, ll = slot & 63;
      int ms = p >> 1, ks = p & 1;
      int row = 64*bt + 16*ms + (ll & 15);
      int k = 64*ch + 32*ks + 8*(ll >> 4);
      *(uint4*)&Ash[slot*8] = *(const uint4*)&hprev[row*512 + k];
    }
#pragma unroll
    for (int i = 0; i < 2; i++) {
      int slot = t + 256*i;
      int p = slot >> 6, ll = slot & 63;
      int ns = p >> 1, ks = p & 1;
      int gcol = 512*ns + 16*jt + (ll & 15);
      int k = 64*ch + 32*ks + 8*(ll >> 4);
      *(uint4*)&Bsh[slot*8] = *(const uint4*)&whhb[gcol*512 + k];
    }
    __syncthreads();
#pragma unroll
    for (int ks = 0; ks < 2; ks++) {
      short8 A0 = *(short8*)&Ash[(((2*mw+0)*2 + ks)*64 + l)*8];
      short8 A1 = *(short8*)&Ash[(((2*mw+1)*2 + ks)*64 + l)*8];
      short8 B0 = *(short8*)&Bsh[(((2*nw+0)*2 + ks)*64 + l)*8];
      short8 B1 = *(short8*)&Bsh[(((2*nw+1)*2 + ks)*64 + l)*8];
      acc[0][0] = MFMA(A0, B0, acc[0][0]);
      acc[0][1] = MFMA(A0, B1, acc[0][1]);
      acc[1][0] = MFMA(A1, B0, acc[1][0]);
      acc[1][1] = MFMA(A1, B1, acc[1][1]);
    }
  }

#pragma unroll
  for (int mt = 0; mt < 2; mt++)
#pragma unroll
  for (int nt = 0; nt < 2; nt++) {
    int cb = 32*nw + 16*nt + (l & 15);
    int rb = 32*mw + 16*mt + (l >> 4)*4;
    f32x4 a = acc[mt][nt];
#pragma unroll
    for (int r = 0; r < 4; r++) gsh[rb + r][cb] = a[r];
  }
  __syncthreads();

  {
    int m = t >> 2, u0 = (t & 3)*4;
    int b = 64*bt + m;
    int j0 = 16*jt + u0;
    float* cp = cbuf + b*512 + j0;
    f32x4 c = *(f32x4*)cp;
    f32x4 cn;
    uint2 hv;
    unsigned short* hs = (unsigned short*)&hv;
#pragma unroll
    for (int i2 = 0; i2 < 4; i2++) {
      float gi = gsh[m][ 0 + u0 + i2];
      float gf = gsh[m][16 + u0 + i2];
      float gg = gsh[m][32 + u0 + i2];
      float go = gsh[m][48 + u0 + i2];
      float ii = 1.f/(1.f + expf(-gi));
      float ff = 1.f/(1.f + expf(-gf));
      float g2 = tanhf(gg);
      float oo = 1.f/(1.f + expf(-go));
      float cv = ff*c[i2] + ii*g2;
      cn[i2] = cv;
      hs[i2] = f2bf(oo * tanhf(cv));
    }
    *(f32x4*)cp = cn;
    *(uint2*)&hnext[b*512 + j0] = hv;
  }
}

// ---------------- K2': persistent cooperative LSTM — all 128 steps ---------
// 256 blocks, 1/CU. Verified runtime XCD roster (R9). Channel discipline
// (R10 lesson — each channel must use ONE rendezvous point, never mixed):
//   h data:  plain stores (dirty in shared XCD L2) + batched inline-asm
//            sc0-only loads (L1-bypass, L2-hit, pipelined). [R10-proven]
//   flags:   volatile store + volatile load (sc0+sc1 pair, rendezvous at
//            the L3 coherence point). [R9-proven]
// R10's bug: sc0-only flag POLL vs sc1 flag STORE -> stale L2 line ->
// 100ms timeout per run. All spins bounded. Agent fallback path = R7.
__global__ __launch_bounds__(256, 1) void k_lstm_all(
    unsigned short* __restrict__ hb0, unsigned short* __restrict__ hb1,
    const unsigned short* __restrict__ whhb,
    const unsigned short* __restrict__ wihb,
    const int* __restrict__ inputs, const int* __restrict__ dirs,
    const unsigned short* __restrict__ linkb,
    const unsigned short* __restrict__ direb,
    const float* __restrict__ bias_sum,
    unsigned int* __restrict__ flags,        // [8 groups][64 u32 stride]
    unsigned int* __restrict__ cnt)          // [0..7] per-XCD, [8] total
{
  const int t = threadIdx.x, w = t >> 6, l = t & 63;
  const int mw = w & 1, nw = w >> 1;

  __shared__ unsigned short Ash[8*2*4*64*8]; // 64KB
  __shared__ float gsh[64][68];              // 17.4KB
  __shared__ int roster[3];                  // jt, bt, loc

  if (t == 0) {
    unsigned xcd;
    asm volatile("s_getreg_b32 %0, hwreg(HW_REG_XCC_ID)" : "=s"(xcd));
    xcd &= 7u;
    unsigned slot = __hip_atomic_fetch_add(&cnt[xcd], 1u, __ATOMIC_RELAXED,
                                           __HIP_MEMORY_SCOPE_AGENT);
    __hip_atomic_fetch_add(&cnt[8], 1u, __ATOMIC_RELEASE,
                           __HIP_MEMORY_SCOPE_AGENT);
    bool ok = true;
    for (int it2 = 0; ; ++it2) {             // one-time grid barrier, bounded
      if (__hip_atomic_load(&cnt[8], __ATOMIC_ACQUIRE,
                            __HIP_MEMORY_SCOPE_AGENT) >= 256u) break;
      if (it2 > 5000000) { ok = false; break; }
      __builtin_amdgcn_s_sleep(2);
    }
    bool uniform = ok;
    for (int x2 = 0; x2 < 8; x2++)
      if (__hip_atomic_load(&cnt[x2], __ATOMIC_RELAXED,
                            __HIP_MEMORY_SCOPE_AGENT) != 32u) uniform = false;
    if (uniform) { roster[0] = (int)slot; roster[1] = (int)xcd; roster[2] = 1; }
    else { roster[0] = (int)(blockIdx.x & 31); roster[1] = (int)(blockIdx.x >> 5);
           roster[2] = 0; }
  }
  __syncthreads();
  const int jt  = roster[0];   // [0,32) unit tile
  const int bt  = roster[1];   // [0,8)  batch group
  const bool loc = roster[2] != 0;

  unsigned int* gf = flags + bt*64;          // 256B stride per group

  // ---- hoist w_hh fragments into registers (once) ----
  short8 Bw[8][2][2];                        // 128 VGPRs
#pragma unroll
  for (int ch = 0; ch < 8; ch++)
#pragma unroll
  for (int ks = 0; ks < 2; ks++)
#pragma unroll
  for (int nsl = 0; nsl < 2; nsl++) {
    int ns = 2*nw + nsl;
    int gcol = 512*ns + 16*jt + (l & 15);
    int k = 64*ch + 32*ks + 8*(l >> 4);
    Bw[ch][ks][nsl] = *(const short8*)&whhb[(int64_t)gcol*512 + k];
  }
  // ---- hoist w_ih fragments (K=160: 5 chunks of 32) ----
  short8 Wx[5][2];                           // 40 VGPRs
#pragma unroll
  for (int ch = 0; ch < 5; ch++)
#pragma unroll
  for (int nsl = 0; nsl < 2; nsl++) {
    int ns = 2*nw + nsl;
    int gcol = 512*ns + 16*jt + (l & 15);
    int k = 32*ch + 8*(l >> 4);
    Wx[ch][nsl] = *(const short8*)&wihb[(int64_t)gcol*160 + k];
  }
  // ---- bias for this thread's two gate columns ----
  float bias_b[2];
#pragma unroll
  for (int nt = 0; nt < 2; nt++) {
    int g = 2*nw + nt;
    bias_b[nt] = bias_sum[512*g + 16*jt + (l & 15)];
  }

  float creg[4] = {0.f, 0.f, 0.f, 0.f};
  const int m = t >> 2, u0 = (t & 3)*4;
  const int bgl = 64*bt + m;
  const int j0 = 16*jt + u0;
  const int kk8 = 8*(l >> 4);
  const int row0 = 64*bt + 32*mw + (l & 15);   // mt=0 batch row
  const int row1 = row0 + 16;                  // mt=1 batch row
  int bad = 0;                               // wave-0 poll timeout latch

  // prologue: x fragments for step 0 (gathered; bit-identical to xb path)
  short8 xf[2][5];                           // 40 VGPRs
  {
    int i0 = inputs[row0*128 + 0], i1 = inputs[row1*128 + 0];
    int d0 = dirs[row0*128 + 0],  d1 = dirs[row1*128 + 0];
#pragma unroll
    for (int ch = 0; ch < 4; ch++) {
      xf[0][ch] = *(const short8*)&linkb[(int64_t)i0*128 + 32*ch + kk8];
      xf[1][ch] = *(const short8*)&linkb[(int64_t)i1*128 + 32*ch + kk8];
    }
    xf[0][4] = *(const short8*)&direb[d0*32 + kk8];
    xf[1][4] = *(const short8*)&direb[d1*32 + kk8];
  }

  for (int s = 0; s < 128; s++) {
    const unsigned short* hp = (s & 1) ? hb1 : hb0;
    unsigned short* hn = (s & 1) ? hb0 : hb1;

    // ---- x-gates for step s (bit-exact with k_gatesx; no h dependency) ----
    uint2 gxr[2][2];
#pragma unroll
    for (int mt = 0; mt < 2; mt++)
#pragma unroll
    for (int nt = 0; nt < 2; nt++) {
      f32x4 a;
      a[0] = bias_b[nt]; a[1] = bias_b[nt]; a[2] = bias_b[nt]; a[3] = bias_b[nt];
#pragma unroll
      for (int ch = 0; ch < 5; ch++)
        a = MFMA(xf[mt][ch], Wx[ch][nt], a);
      unsigned short* ps = (unsigned short*)&gxr[mt][nt];
      ps[0] = f2bf(a[0]); ps[1] = f2bf(a[1]); ps[2] = f2bf(a[2]); ps[3] = f2bf(a[3]);
    }

    // ---- prefetch x fragments for step s+1 (plain cached gathers; tables
    // are read-only and L2-resident) ----
    {
      int sn = (s + 1 < 128) ? s + 1 : 127;
      int i0 = inputs[row0*128 + sn], i1 = inputs[row1*128 + sn];
      int d0 = dirs[row0*128 + sn],  d1 = dirs[row1*128 + sn];
#pragma unroll
      for (int ch = 0; ch < 4; ch++) {
        xf[0][ch] = *(const short8*)&linkb[(int64_t)i0*128 + 32*ch + kk8];
        xf[1][ch] = *(const short8*)&linkb[(int64_t)i1*128 + 32*ch + kk8];
      }
      xf[0][4] = *(const short8*)&direb[d0*32 + kk8];
      xf[1][4] = *(const short8*)&direb[d1*32 + kk8];
    }

    // ---- wait: all 32 group flags >= s (wave 0 polls; BOUNDED).
    // volatile load pairs with the volatile flag store (R9-proven). ----
    if (s > 0) {
      if (w == 0 && !bad) {
        unsigned tgt = (unsigned)s;
        for (int it2 = 0; ; ++it2) {
          unsigned v;
          if (loc) v = *(volatile const unsigned*)&gf[l & 31];
          else     v = __hip_atomic_load(&gf[l & 31], __ATOMIC_RELAXED,
                                         __HIP_MEMORY_SCOPE_AGENT);
          if (__all((int)(v >= tgt))) break;
          if (it2 > 400000) { bad = 1; break; }    // terminate, don't hang
          __builtin_amdgcn_s_sleep(1);
        }
      }
      __syncthreads();
    }

    // ---- stage A tile (64 rows x K=512) -> LDS ----
    if (loc) {
      // h channel: plain stores landed dirty in this XCD's shared L2;
      // sc0-only batched loads read them (L1-bypass), fully pipelined.
      uint4 tmp[16];
#pragma unroll
      for (int i = 0; i < 16; i++) {
        int p = w*16 + i;                    // = ch*8 + ks*4 + ms
        int ms = p & 3, ks = (p >> 2) & 1, ch = p >> 3;
        int row = 64*bt + 16*ms + (l & 15);
        int k = 64*ch + 32*ks + 8*(l >> 4);
        const unsigned short* src = hp + (int64_t)row*512 + k;
        asm volatile("global_load_dwordx4 %0, %1, off sc0"
                     : "=v"(tmp[i]) : "v"(src) : "memory");
      }
      asm volatile("s_waitcnt vmcnt(0)" ::: "memory");
      __builtin_amdgcn_sched_barrier(0);
#pragma unroll
      for (int i = 0; i < 16; i++) {
        int p = w*16 + i;
        *(uint4*)&Ash[(p*64 + l)*8] = tmp[i];
      }
    } else {
      // agent-scope loads from the L3 coherence point (R7-proven)
#pragma unroll
      for (int i = 0; i < 16; i++) {
        int p = w*16 + i;
        int ms = p & 3, ks = (p >> 2) & 1, ch = p >> 3;
        int row = 64*bt + 16*ms + (l & 15);
        int k = 64*ch + 32*ks + 8*(l >> 4);
        const unsigned long long* src =
            (const unsigned long long*)(hp + (int64_t)row*512 + k);
        unsigned long long d0 = __hip_atomic_load(src,     __ATOMIC_RELAXED,
                                                  __HIP_MEMORY_SCOPE_AGENT);
        unsigned long long d1 = __hip_atomic_load(src + 1, __ATOMIC_RELAXED,
                                                  __HIP_MEMORY_SCOPE_AGENT);
        unsigned long long tmp2[2] = {d0, d1};
        *(uint4*)&Ash[(p*64 + l)*8] = *(const uint4*)tmp2;
      }
    }
    __syncthreads();

    f32x4 acc[2][2];
#pragma unroll
    for (int mt = 0; mt < 2; mt++)
#pragma unroll
    for (int nt = 0; nt < 2; nt++) {
      const unsigned short* pk = (const unsigned short*)&gxr[mt][nt];
      f32x4 v;
      v[0] = bf2f(pk[0]); v[1] = bf2f(pk[1]); v[2] = bf2f(pk[2]); v[3] = bf2f(pk[3]);
      acc[mt][nt] = v;
    }

#pragma unroll
    for (int ch = 0; ch < 8; ch++)
#pragma unroll
    for (int ks = 0; ks < 2; ks++) {
      short8 A0 = *(short8*)&Ash[((ch*8 + ks*4 + 2*mw + 0)*64 + l)*8];
      short8 A1 = *(short8*)&Ash[((ch*8 + ks*4 + 2*mw + 1)*64 + l)*8];
      acc[0][0] = MFMA(A0, Bw[ch][ks][0], acc[0][0]);
      acc[0][1] = MFMA(A0, Bw[ch][ks][1], acc[0][1]);
      acc[1][0] = MFMA(A1, Bw[ch][ks][0], acc[1][0]);
      acc[1][1] = MFMA(A1, Bw[ch][ks][1], acc[1][1]);
    }

    // gate exchange
#pragma unroll
    for (int mt = 0; mt < 2; mt++)
#pragma unroll
    for (int nt = 0; nt < 2; nt++) {
      int cb = 32*nw + 16*nt + (l & 15);
      int rb = 32*mw + 16*mt + (l >> 4)*4;
      f32x4 a = acc[mt][nt];
#pragma unroll
      for (int r = 0; r < 4; r++) gsh[rb + r][cb] = a[r];
    }
    __syncthreads();

    {
      union { unsigned short hs[4]; unsigned long long v; } hv;
#pragma unroll
      for (int i2 = 0; i2 < 4; i2++) {
        float gi = gsh[m][ 0 + u0 + i2];
        float gf2 = gsh[m][16 + u0 + i2];
        float gg = gsh[m][32 + u0 + i2];
        float go = gsh[m][48 + u0 + i2];
        float ii = 1.f/(1.f + expf(-gi));
        float ff = 1.f/(1.f + expf(-gf2));
        float g2 = tanhf(gg);
        float oo = 1.f/(1.f + expf(-go));
        float cv = ff*creg[i2] + ii*g2;
        creg[i2] = cv;
        hv.hs[i2] = f2bf(oo * tanhf(cv));
      }
      if (loc)   // plain store: dirty line in this XCD's L2 (exchange point)
        *(unsigned long long*)&hn[(int64_t)bgl*512 + j0] = hv.v;
      else       // agent store: write-through to the L3 coherence point
        __hip_atomic_store((unsigned long long*)&hn[(int64_t)bgl*512 + j0],
                           hv.v, __ATOMIC_RELAXED, __HIP_MEMORY_SCOPE_AGENT);
    }

    // __syncthreads drains vmcnt(0) in every wave (h stores ACKed at the
    // exchange point) BEFORE the flag post -> release without any fence.
    __syncthreads();
    if (t == 0) {
      asm volatile("s_waitcnt vmcnt(0)" ::: "memory");  // belt-and-braces
      if (loc) *(volatile unsigned*)&gf[jt] = (unsigned)(s + 1);
      else __hip_atomic_store(&gf[jt], (unsigned)(s + 1), __ATOMIC_RELAXED,
                              __HIP_MEMORY_SCOPE_AGENT);
    }
  }
}

// ---------------- generic bf16 GEMM: C = act(A(MxK) * B(NxK)^T + bias) -----
// MODE 0: bf16 out + bias + relu;  MODE 1: f32 out + bias, cols < nreal;
// MODE 2: f32 out replicated x5 (pred_hard), row stride 40960.
template<int MODE>
__global__ __launch_bounds__(256) void k_gemm(
    const unsigned short* __restrict__ A, int lda,
    const unsigned short* __restrict__ Bm, int ldb, int nreal,
    const float* __restrict__ bias,
    void* __restrict__ outp, int ldo, int nchunks)
{
  const int bX = blockIdx.x, bY = blockIdx.y;
  const int t = threadIdx.x, w = t >> 6, l = t & 63;
  const int mw = w & 1, nw = w >> 1;
  __shared__ unsigned short Ash[4*2*64*8];
  __shared__ unsigned short Bsh[4*2*64*8];

  f32x4 acc[2][2];
  f32x4 z; z[0] = 0.f; z[1] = 0.f; z[2] = 0.f; z[3] = 0.f;
  acc[0][0] = z; acc[0][1] = z; acc[1][0] = z; acc[1][1] = z;

  for (int ch = 0; ch < nchunks; ch++) {
    __syncthreads();
#pragma unroll
    for (int i = 0; i < 2; i++) {
      int slot = t + 256*i;
      int p = slot >> 6, ll = slot & 63;
      int ms = p >> 1, ks = p & 1;
      int row = 64*bY + 16*ms + (ll & 15);
      int k = 64*ch + 32*ks + 8*(ll >> 4);
      *(uint4*)&Ash[slot*8] = *(const uint4*)&A[(int64_t)row*lda + k];
    }
#pragma unroll
    for (int i = 0; i < 2; i++) {
      int slot = t + 256*i;
      int p = slot >> 6, ll = slot & 63;
      int ns = p >> 1, ks = p & 1;
      int row = 64*bX + 16*ns + (ll & 15);
      if (row >= nreal) row = nreal - 1;   // clamp (garbage cols masked later)
      int k = 64*ch + 32*ks + 8*(ll >> 4);
      *(uint4*)&Bsh[slot*8] = *(const uint4*)&Bm[(int64_t)row*ldb + k];
    }
    __syncthreads();
#pragma unroll
    for (int ks = 0; ks < 2; ks++) {
      short8 A0 = *(short8*)&Ash[(((2*mw+0)*2 + ks)*64 + l)*8];
      short8 A1 = *(short8*)&Ash[(((2*mw+1)*2 + ks)*64 + l)*8];
      short8 B0 = *(short8*)&Bsh[(((2*nw+0)*2 + ks)*64 + l)*8];
      short8 B1 = *(short8*)&Bsh[(((2*nw+1)*2 + ks)*64 + l)*8];
      acc[0][0] = MFMA(A0, B0, acc[0][0]);
      acc[0][1] = MFMA(A0, B1, acc[0][1]);
      acc[1][0] = MFMA(A1, B0, acc[1][0]);
      acc[1][1] = MFMA(A1, B1, acc[1][1]);
    }
  }

#pragma unroll
  for (int mt = 0; mt < 2; mt++)
#pragma unroll
  for (int nt = 0; nt < 2; nt++) {
    int n = 64*bX + 32*nw + 16*nt + (l & 15);
    int rb = 64*bY + 32*mw + 16*mt + (l >> 4)*4;
    f32x4 a = acc[mt][nt];
    if (MODE == 0) {
      float bv = bias[n];
#pragma unroll
      for (int r = 0; r < 4; r++) {
        float v = a[r] + bv; v = v > 0.f ? v : 0.f;
        ((unsigned short*)outp)[(int64_t)(rb + r)*ldo + n] = f2bf(v);
      }
    } else if (MODE == 1) {
      if (n < nreal) {
        float bv = bias[n];
#pragma unroll
        for (int r = 0; r < 4; r++)
          ((float*)outp)[(int64_t)(rb + r)*ldo + n] = a[r] + bv;
      }
    } else {
#pragma unroll
      for (int r = 0; r < 4; r++) {
        float v = a[r];
        float* o = (float*)outp + (int64_t)(rb + r)*40960 + n;
#pragma unroll
        for (int p5 = 0; p5 < 5; p5++) o[p5*8192] = v;
      }
    }
  }
}

// ---------------- K4: softmax head, top-2, loss, count, query, pdr copy ----
__global__ __launch_bounds__(256) void k_head(
    const float* __restrict__ logits, const int* __restrict__ inputs,
    const int* __restrict__ goal, const int* __restrict__ ldm,
    const float* __restrict__ link, const float* __restrict__ dire,
    const float* __restrict__ pdr, unsigned short* __restrict__ qb,
    float* __restrict__ out)
{
  const int blk = blockIdx.x, t = threadIdx.x;
  __shared__ int idxsh[64][2];
  __shared__ float redf[256];
  __shared__ int redi[256];

  if (t < 64) {                       // top-2 for this block's 64 rows
    int b = 64*blk + t;
    float v[8];
#pragma unroll
    for (int i = 0; i < 8; i++) v[i] = logits[b*8 + i];
    int i0 = 0; float m0 = v[0];
#pragma unroll
    for (int i = 1; i < 8; i++) if (v[i] > m0) { m0 = v[i]; i0 = i; }
    int i1 = -1; float m1 = -3.4e38f;
#pragma unroll
    for (int i = 0; i < 8; i++) if (i != i0 && v[i] > m1) { m1 = v[i]; i1 = i; }
    idxsh[t][0] = i0; idxsh[t][1] = i1;
  }
  __syncthreads();
  {                                   // query = le + pad(0.5*(de0+de1)) (bf16)
    int rl = t >> 2, kc = (t & 3) * 32;
    int b = 64*blk + rl;
    int last = inputs[b*128 + 127];
    const float* le = link + (int64_t)last*128 + kc;
    int i0 = idxsh[rl][0], i1 = idxsh[rl][1];
    unsigned short q[32] __attribute__((aligned(16)));
#pragma unroll
    for (int k = 0; k < 32; k++) {
      float v = le[k];
      if (kc == 0) v += 0.5f*(dire[(i0+1)*32 + k] + dire[(i1+1)*32 + k]);
      q[k] = f2bf(v);
    }
    uint4* dst = (uint4*)&qb[b*128 + kc];
#pragma unroll
    for (int x = 0; x < 4; x++) dst[x] = ((uint4*)q)[x];
  }
  if (blk == 0) {                     // loss + direction_correct over all rows
    float lsum = 0.f; int csum = 0;
    for (int rr = t; rr < 512; rr += 256) {
      float v[8];
#pragma unroll
      for (int i = 0; i < 8; i++) v[i] = logits[rr*8 + i];
      float mx = v[0];
#pragma unroll
      for (int i = 1; i < 8; i++) mx = v[i] > mx ? v[i] : mx;
      float se = 0.f;
#pragma unroll
      for (int i = 0; i < 8; i++) se += expf(v[i] - mx);
      float lse = logf(se);
      int last = inputs[rr*128 + 127];
      int lbl = ldm[(int64_t)(last - 1)*8192 + goal[rr]];
      lsum += v[lbl] - mx - lse;      // ls2 == log_softmax (idempotent)
      int i0 = 0; float m0 = v[0];
#pragma unroll
      for (int i = 1; i < 8; i++) if (v[i] > m0) { m0 = v[i]; i0 = i; }
      int i1 = -1; float m1 = -3.4e38f;
#pragma unroll
      for (int i = 0; i < 8; i++) if (i != i0 && v[i] > m1) { m1 = v[i]; i1 = i; }
      if (i0 == lbl || i1 == lbl) csum++;
    }
    redf[t] = lsum; redi[t] = csum;
    __syncthreads();
    for (int o2 = 128; o2 > 0; o2 >>= 1) {
      if (t < o2) { redf[t] += redf[t + o2]; redi[t] += redi[t + o2]; }
      __syncthreads();
    }
    if (t == 0) {
      out[20992000] = -redf[0] / 512.f * 5.f;
      out[20992001] = (float)redi[0];
    }
  }
  for (int i = 0; i < 10; i++) {      // pred_d_rand passthrough
    int idx = blk*2560 + t*10 + i;
    out[20971520 + idx] = pdr[idx];
  }
}

// ---------------- host ----------------
extern "C" void kernel_launch(void* const* d_in, const int* in_sizes, int n_in,
                              void* d_out, int out_size, void* d_ws, size_t ws_size,
                              hipStream_t stream)
{
  const int* inputs = (const int*)d_in[0];
  const int* dirs   = (const int*)d_in[1];
  const int* goal   = (const int*)d_in[2];
  const int* ldm    = (const int*)d_in[3];
  const float* pdr  = (const float*)d_in[4];
  const float* link = (const float*)d_in[5];
  const float* dire = (const float*)d_in[6];
  const float* w_ih = (const float*)d_in[7];
  const float* b_ih = (const float*)d_in[8];
  const float* w_hh = (const float*)d_in[9];
  const float* b_hh = (const float*)d_in[10];
  const float* W1   = (const float*)d_in[11];
  const float* b1   = (const float*)d_in[12];
  const float* W2   = (const float*)d_in[13];
  const float* b2   = (const float*)d_in[14];
  const float* W3   = (const float*)d_in[15];
  const float* b3   = (const float*)d_in[16];
  float* out = (float*)d_out;

  char* wsp = (char*)d_ws;
  size_t off = 0;
  auto alloc = [&](size_t bytes) { char* p = wsp + off; off += (bytes + 255) & ~(size_t)255; return p; };
  unsigned short* xb    = (unsigned short*)alloc(10485760ull*2);  // fallback only
  unsigned short* wihb  = (unsigned short*)alloc(327680ull*2);
  unsigned short* whhb  = (unsigned short*)alloc(1048576ull*2);
  unsigned short* w1b   = (unsigned short*)alloc(262144ull*2);
  unsigned short* w2b   = (unsigned short*)alloc(262144ull*2);
  unsigned short* w3b   = (unsigned short*)alloc(4096ull*2);
  unsigned short* linkb = (unsigned short*)alloc(1048704ull*2);
  unsigned short* direb = (unsigned short*)alloc(288ull*2);
  float* bias_sum       = (float*)alloc(2048ull*4);
  unsigned short* gxb   = (unsigned short*)alloc(134217728ull*2);  // fallback only
  unsigned short* hb0   = (unsigned short*)alloc(262144ull*2);
  unsigned short* hb1   = (unsigned short*)alloc(262144ull*2);
  float* cbuf           = (float*)alloc(262144ull*4);
  unsigned short* z1b   = (unsigned short*)alloc(262144ull*2);
  unsigned short* z2b   = (unsigned short*)alloc(262144ull*2);
  float* logits         = (float*)alloc(4096ull*4);
  unsigned short* qb    = (unsigned short*)alloc(65536ull*2);
  unsigned int* flags   = (unsigned int*)alloc(4096);   // 8x64 u32 (256B/grp)
  unsigned int* cnt     = (unsigned int*)alloc(256);    // roster counters

  hipMemsetAsync(hb0, 0, 262144ull*2, stream);    // h0 = 0 (bf16 zeros)
  hipMemsetAsync(flags, 0, 4096, stream);         // flags = 0
  hipMemsetAsync(cnt, 0, 256, stream);            // roster counters = 0

  k_prep<<<11546, 256, 0, stream>>>(link, dire, w_ih, w_hh, W1, W2, W3,
                                    b_ih, b_hh, wihb, whhb, w1b, w2b, w3b,
                                    linkb, direb, bias_sum);

  {
    unsigned short* a0 = hb0; unsigned short* a1 = hb1;
    const unsigned short* a2 = whhb; const unsigned short* a3 = wihb;
    const int* a4 = inputs; const int* a5 = dirs;
    const unsigned short* a6 = linkb; const unsigned short* a7 = direb;
    const float* a8 = bias_sum;
    unsigned int* a9 = flags; unsigned int* a10 = cnt;
    void* kargs[11] = { &a0, &a1, &a2, &a3, &a4, &a5, &a6, &a7, &a8, &a9, &a10 };
    hipError_t ce = hipLaunchCooperativeKernel((const void*)k_lstm_all,
                                               dim3(256,1,1), dim3(256,1,1),
                                               kargs, 0, stream);
    if (ce != hipSuccess) {
      // fallback: materialize xb + gx then per-step launches (verified path)
      k_prep_xb<<<40960, 256, 0, stream>>>(inputs, dirs, link, dire, xb);
      k_gatesx<<<dim3(16,2,128), 256, 0, stream>>>(xb, wihb, bias_sum, gxb);
      hipMemsetAsync(cbuf, 0, 262144ull*4, stream);
      for (int s = 0; s < 128; s++) {
        const unsigned short* hp = (s & 1) ? hb1 : hb0;
        unsigned short* hn = (s & 1) ? hb0 : hb1;
        k_lstm_step<<<dim3(32,8), 256, 0, stream>>>(hp, hn, cbuf, whhb, gxb, s);
      }
    }
  }
  // final h in hb0 (128 steps, even)
  k_gemm<0><<<dim3(8,8), 256, 0, stream>>>(hb0, 512, w1b, 512, 512, b1, z1b, 512, 8);
  k_gemm<0><<<dim3(8,8), 256, 0, stream>>>(z1b, 512, w2b, 512, 512, b2, z2b, 512, 8);
  k_gemm<1><<<dim3(1,8), 256, 0, stream>>>(z2b, 512, w3b, 512, 8, b3, logits, 8, 8);
  k_head<<<8, 256, 0, stream>>>(logits, inputs, goal, ldm, link, dire, pdr, qb, out);
  k_gemm<2><<<dim3(128,8), 256, 0, stream>>>(qb, 128, linkb + 128, 128, 8192, nullptr, out, 0, 2);
}

// Round 13
// 1291.304 us; speedup vs baseline: 36.9002x; 1.0198x over previous
//
#include <hip/hip_runtime.h>
#include <stdint.h>

// Sizes: B=512 S=128 NE=8192 ED=128 DD=32 ND=8 H=512 G=2048 PL=5 IN=160

typedef __attribute__((ext_vector_type(8))) short short8;
typedef __attribute__((ext_vector_type(4))) float f32x4;

__device__ __forceinline__ unsigned short f2bf(float f) {
  union { float f; unsigned u; } v; v.f = f;
  return (unsigned short)((v.u + 0x7fffu + ((v.u >> 16) & 1u)) >> 16);
}
__device__ __forceinline__ float bf2f(unsigned short h) {
  union { unsigned u; float f; } v; v.u = ((unsigned)h) << 16;
  return v.f;
}
__device__ __forceinline__ f32x4 MFMA(short8 a, short8 b, f32x4 c) {
  return __builtin_amdgcn_mfma_f32_16x16x32_bf16(a, b, c, 0, 0, 0);
}

// ---------------- K0: weight bf16 conversions + tables + bias sum ----------
__global__ __launch_bounds__(256) void k_prep(
    const float* __restrict__ link, const float* __restrict__ dire,
    const float* __restrict__ w_ih, const float* __restrict__ w_hh,
    const float* __restrict__ W1, const float* __restrict__ W2,
    const float* __restrict__ W3, const float* __restrict__ b_ih,
    const float* __restrict__ b_hh,
    unsigned short* __restrict__ wihb, unsigned short* __restrict__ whhb,
    unsigned short* __restrict__ w1b, unsigned short* __restrict__ w2b,
    unsigned short* __restrict__ w3b, unsigned short* __restrict__ linkb,
    unsigned short* __restrict__ direb, float* __restrict__ bias_sum)
{
  int64_t e = (int64_t)blockIdx.x * 256 + threadIdx.x;
  if (e < 327680)  { wihb[e] = f2bf(w_ih[e]); return; }
  e -= 327680;
  if (e < 1048576) { whhb[e] = f2bf(w_hh[e]); return; }
  e -= 1048576;
  if (e < 262144)  { w1b[e] = f2bf(W1[e]); return; }
  e -= 262144;
  if (e < 262144)  { w2b[e] = f2bf(W2[e]); return; }
  e -= 262144;
  if (e < 4096)    { w3b[e] = f2bf(W3[e]); return; }
  e -= 4096;
  if (e < 1048704) { linkb[e] = f2bf(link[e]); return; }
  e -= 1048704;
  if (e < 288)     { direb[e] = f2bf(dire[e]); return; }
  e -= 288;
  if (e < 2048)    { bias_sum[e] = b_ih[e] + b_hh[e]; return; }
}

// ---------------- K0b (fallback only): gather xb -----------------------------
__global__ __launch_bounds__(256) void k_prep_xb(
    const int* __restrict__ inputs, const int* __restrict__ dirs,
    const float* __restrict__ link, const float* __restrict__ dire,
    unsigned short* __restrict__ xb)
{
  int ei = blockIdx.x * 256 + threadIdx.x;
  if (ei >= 10485760) return;
  int s = ei / 81920;
  int r = ei % 81920;
  int b = r / 160, k = r % 160;
  float v;
  if (k < 128) v = link[(int64_t)inputs[b*128 + s]*128 + k];
  else         v = dire[dirs[b*128 + s]*32 + (k - 128)];
  xb[ei] = f2bf(v);
}

// ---------------- K1 (fallback only): gates_x = x @ w_ih^T + bias_sum ------
__global__ __launch_bounds__(256) void k_gatesx(
    const unsigned short* __restrict__ xb, const unsigned short* __restrict__ wihb,
    const float* __restrict__ bias_sum, unsigned short* __restrict__ gx)
{
  const int jt1 = blockIdx.x;   // [0,16): 32 hidden units each
  const int bt2 = blockIdx.y;   // [0,2):  256 batch rows each
  const int s   = blockIdx.z;   // [0,128)
  const int t = threadIdx.x, w = t >> 6, l = t & 63;

  __shared__ unsigned short Ash[16*64*8];  // [ms16][l64][8]  16KB
  __shared__ unsigned short Bsh[8*64*8];   // [ns8][l64][8]    8KB

  f32x4 acc[4][8];
#pragma unroll
  for (int ns = 0; ns < 8; ns++) {
    int dj = ns >> 2, g = ns & 3;
    int gcol = 512*g + 32*jt1 + 16*dj + (l & 15);
    float bv = bias_sum[gcol];
    f32x4 b4; b4[0] = bv; b4[1] = bv; b4[2] = bv; b4[3] = bv;
#pragma unroll
    for (int msl = 0; msl < 4; msl++) acc[msl][ns] = b4;
  }
  const unsigned short* xrow = xb + (int64_t)(s*512 + bt2*256)*160;

  for (int ch = 0; ch < 5; ch++) {   // K=160, chunks of 32
    __syncthreads();
#pragma unroll
    for (int i = 0; i < 4; i++) {    // A: 1024 slots of 16B
      int slot = t + 256*i;
      int ms = slot >> 6, ll = slot & 63;
      int row = 16*ms + (ll & 15);
      int k = 32*ch + 8*(ll >> 4);
      *(uint4*)&Ash[slot*8] = *(const uint4*)&xrow[row*160 + k];
    }
#pragma unroll
    for (int i = 0; i < 2; i++) {    // B: 512 slots
      int slot = t + 256*i;
      int ns = slot >> 6, ll = slot & 63;
      int dj = ns >> 2, g = ns & 3;
      int gcol = 512*g + 32*jt1 + 16*dj + (ll & 15);
      int k = 32*ch + 8*(ll >> 4);
      *(uint4*)&Bsh[slot*8] = *(const uint4*)&wihb[gcol*160 + k];
    }
    __syncthreads();
    short8 Bf[8];
#pragma unroll
    for (int ns = 0; ns < 8; ns++) Bf[ns] = *(short8*)&Bsh[(ns*64 + l)*8];
#pragma unroll
    for (int msl = 0; msl < 4; msl++) {
      short8 Af = *(short8*)&Ash[((4*w + msl)*64 + l)*8];
#pragma unroll
      for (int ns = 0; ns < 8; ns++)
        acc[msl][ns] = MFMA(Af, Bf[ns], acc[msl][ns]);
    }
  }
  // epilogue: scatter into step-kernel fragment order (R1 layout)
#pragma unroll
  for (int msl = 0; msl < 4; msl++) {
    int ms1 = 4*w + msl;
    int brow0 = 256*bt2 + 16*ms1;
    int bt = brow0 >> 6;
    int ms2 = (brow0 >> 4) & 3;
    int mw = ms2 >> 1, mt = ms2 & 1;
#pragma unroll
    for (int ns = 0; ns < 8; ns++) {
      int dj = ns >> 2, g = ns & 3;
      int jt2 = 2*jt1 + dj;
      int nw = g >> 1, nt = g & 1;
      int w2 = 2*nw + mw;
      int64_t idx = ((((((int64_t)s*32 + jt2)*8 + bt)*4 + w2)*2 + mt)*2 + nt)*64 + l;
      f32x4 a = acc[msl][ns];
      uint2 pk;
      unsigned short* ps = (unsigned short*)&pk;
      ps[0] = f2bf(a[0]); ps[1] = f2bf(a[1]); ps[2] = f2bf(a[2]); ps[3] = f2bf(a[3]);
      *(uint2*)&gx[idx*4] = pk;
    }
  }
}

// ---------------- K2 (fallback path): one LSTM time step (launched 128x) ----
__global__ __launch_bounds__(256) void k_lstm_step(
    const unsigned short* __restrict__ hprev, unsigned short* __restrict__ hnext,
    float* __restrict__ cbuf, const unsigned short* __restrict__ whhb,
    const unsigned short* __restrict__ gx, int s)
{
  const int jt = blockIdx.x;  // [0,32)
  const int bt = blockIdx.y;  // [0,8)
  const int t = threadIdx.x, w = t >> 6, l = t & 63;
  const int mw = w & 1, nw = w >> 1;

  __shared__ unsigned short Ash[4*2*64*8];  // 8KB
  __shared__ unsigned short Bsh[4*2*64*8];  // 8KB
  __shared__ float gsh[64][68];

  f32x4 acc[2][2];
#pragma unroll
  for (int mt = 0; mt < 2; mt++)
#pragma unroll
  for (int nt = 0; nt < 2; nt++) {
    int64_t idx = ((((((int64_t)s*32 + jt)*8 + bt)*4 + w)*2 + mt)*2 + nt)*64 + l;
    uint2 raw = *(const uint2*)(gx + idx*4);
    const unsigned short* pk = (const unsigned short*)&raw;
    f32x4 v;
    v[0] = bf2f(pk[0]); v[1] = bf2f(pk[1]); v[2] = bf2f(pk[2]); v[3] = bf2f(pk[3]);
    acc[mt][nt] = v;
  }

  for (int ch = 0; ch < 8; ch++) {
    __syncthreads();
#pragma unroll
    for (int i = 0; i < 2; i++) {
      int slot = t + 256*i;
      int p = slot >> 6, ll = slot & 63;
      int ms = p >> 1, ks = p & 1;
      int row = 64*bt + 16*ms + (ll & 15);
      int k = 64*ch + 32*ks + 8*(ll >> 4);
      *(uint4*)&Ash[slot*8] = *(const uint4*)&hprev[row*512 + k];
    }
#pragma unroll
    for (int i = 0; i < 2; i++) {
      int slot = t + 256*i;
      int p = slot >> 6, ll = slot & 63;
      int ns = p >> 1, ks = p & 1;
      int gcol = 512*ns + 16*jt + (ll & 15);
      int k = 64*ch + 32*ks + 8*(ll >> 4);
      *(uint4*)&Bsh[slot*8] = *(const uint4*)&whhb[gcol*512 + k];
    }
    __syncthreads();
#pragma unroll
    for (int ks = 0; ks < 2; ks++) {
      short8 A0 = *(short8*)&Ash[(((2*mw+0)*2 + ks)*64 + l)*8];
      short8 A1 = *(short8*)&Ash[(((2*mw+1)*2 + ks)*64 + l)*8];
      short8 B0 = *(short8*)&Bsh[(((2*nw+0)*2 + ks)*64 + l)*8];
      short8 B1 = *(short8*)&Bsh[(((2*nw+1)*2 + ks)*64 + l)*8];
      acc[0][0] = MFMA(A0, B0, acc[0][0]);
      acc[0][1] = MFMA(A0, B1, acc[0][1]);
      acc[1][0] = MFMA(A1, B0, acc[1][0]);
      acc[1][1] = MFMA(A1, B1, acc[1][1]);
    }
  }

#pragma unroll
  for (int mt = 0; mt < 2; mt++)
#pragma unroll
  for (int nt = 0; nt < 2; nt++) {
    int cb = 32*nw + 16*nt + (l & 15);
    int rb = 32*mw + 16*mt + (l >> 4)*4;
    f32x4 a = acc[mt][nt];
#pragma unroll
    for (int r = 0; r < 4; r++) gsh[rb + r][cb] = a[r];
  }
  __syncthreads();

  {
    int m = t >> 2, u0 = (t & 3)*4;
    int b = 64*bt + m;
    int j0 = 16*jt + u0;
    float* cp = cbuf + b*512 + j0;
    f32x4 c = *(f32x4*)cp;
    f32x4 cn;
    uint2 hv;
    unsigned short* hs = (unsigned short*)&hv;
#pragma unroll
    for (int i2 = 0; i2 < 4; i2++) {
      float gi = gsh[m][ 0 + u0 + i2];
      float gf = gsh[m][16 + u0 + i2];
      float gg = gsh[m][32 + u0 + i2];
      float go = gsh[m][48 + u0 + i2];
      float ii = 1.f/(1.f + expf(-gi));
      float ff = 1.f/(1.f + expf(-gf));
      float g2 = tanhf(gg);
      float oo = 1.f/(1.f + expf(-go));
      float cv = ff*c[i2] + ii*g2;
      cn[i2] = cv;
      hs[i2] = f2bf(oo * tanhf(cv));
    }
    *(f32x4*)cp = cn;
    *(uint2*)&hnext[b*512 + j0] = hv;
  }
}

// ---------------- K2': persistent cooperative LSTM — all 128 steps ---------
// 256 blocks, 1/CU. Verified runtime XCD roster (R9). Channel discipline
// (R10/R11 lessons — each channel uses ONE matched rendezvous pair):
//   h data (loc):  plain stores (dirty in shared XCD L2) + batched sc0-only
//                  loads (L1-bypass, L2-hit, pipelined). [R11-proven]
//   flags  (loc):  plain store + sc0-only tight poll — SAME L2 pair as h
//                  (R11 had volatile/volatile at L3: two ~500cy L3 legs +
//                  s_sleep granularity per step; L2 pair cuts both).
//   agent fallback path keeps R7 volatile/agent semantics.
// All spins bounded (terminate, don't hang — R8 lesson).
__global__ __launch_bounds__(256, 1) void k_lstm_all(
    unsigned short* __restrict__ hb0, unsigned short* __restrict__ hb1,
    const unsigned short* __restrict__ whhb,
    const unsigned short* __restrict__ wihb,
    const int* __restrict__ inputs, const int* __restrict__ dirs,
    const unsigned short* __restrict__ linkb,
    const unsigned short* __restrict__ direb,
    const float* __restrict__ bias_sum,
    unsigned int* __restrict__ flags,        // [8 groups][64 u32 stride]
    unsigned int* __restrict__ cnt)          // [0..7] per-XCD, [8] total
{
  const int t = threadIdx.x, w = t >> 6, l = t & 63;
  const int mw = w & 1, nw = w >> 1;

  __shared__ unsigned short Ash[8*2*4*64*8]; // 64KB
  __shared__ float gsh[64][68];              // 17.4KB
  __shared__ int roster[3];                  // jt, bt, loc

  if (t == 0) {
    unsigned xcd;
    asm volatile("s_getreg_b32 %0, hwreg(HW_REG_XCC_ID)" : "=s"(xcd));
    xcd &= 7u;
    unsigned slot = __hip_atomic_fetch_add(&cnt[xcd], 1u, __ATOMIC_RELAXED,
                                           __HIP_MEMORY_SCOPE_AGENT);
    __hip_atomic_fetch_add(&cnt[8], 1u, __ATOMIC_RELEASE,
                           __HIP_MEMORY_SCOPE_AGENT);
    bool ok = true;
    for (int it2 = 0; ; ++it2) {             // one-time grid barrier, bounded
      if (__hip_atomic_load(&cnt[8], __ATOMIC_ACQUIRE,
                            __HIP_MEMORY_SCOPE_AGENT) >= 256u) break;
      if (it2 > 5000000) { ok = false; break; }
      __builtin_amdgcn_s_sleep(2);
    }
    bool uniform = ok;
    for (int x2 = 0; x2 < 8; x2++)
      if (__hip_atomic_load(&cnt[x2], __ATOMIC_RELAXED,
                            __HIP_MEMORY_SCOPE_AGENT) != 32u) uniform = false;
    if (uniform) { roster[0] = (int)slot; roster[1] = (int)xcd; roster[2] = 1; }
    else { roster[0] = (int)(blockIdx.x & 31); roster[1] = (int)(blockIdx.x >> 5);
           roster[2] = 0; }
  }
  __syncthreads();
  const int jt  = roster[0];   // [0,32) unit tile
  const int bt  = roster[1];   // [0,8)  batch group
  const bool loc = roster[2] != 0;

  unsigned int* gf = flags + bt*64;          // 256B stride per group

  // ---- hoist w_hh fragments into registers (once) ----
  short8 Bw[8][2][2];                        // 128 VGPRs
#pragma unroll
  for (int ch = 0; ch < 8; ch++)
#pragma unroll
  for (int ks = 0; ks < 2; ks++)
#pragma unroll
  for (int nsl = 0; nsl < 2; nsl++) {
    int ns = 2*nw + nsl;
    int gcol = 512*ns + 16*jt + (l & 15);
    int k = 64*ch + 32*ks + 8*(l >> 4);
    Bw[ch][ks][nsl] = *(const short8*)&whhb[(int64_t)gcol*512 + k];
  }
  // ---- hoist w_ih fragments (K=160: 5 chunks of 32) ----
  short8 Wx[5][2];                           // 40 VGPRs
#pragma unroll
  for (int ch = 0; ch < 5; ch++)
#pragma unroll
  for (int nsl = 0; nsl < 2; nsl++) {
    int ns = 2*nw + nsl;
    int gcol = 512*ns + 16*jt + (l & 15);
    int k = 32*ch + 8*(l >> 4);
    Wx[ch][nsl] = *(const short8*)&wihb[(int64_t)gcol*160 + k];
  }
  // ---- bias for this thread's two gate columns ----
  float bias_b[2];
#pragma unroll
  for (int nt = 0; nt < 2; nt++) {
    int g = 2*nw + nt;
    bias_b[nt] = bias_sum[512*g + 16*jt + (l & 15)];
  }

  float creg[4] = {0.f, 0.f, 0.f, 0.f};
  const int m = t >> 2, u0 = (t & 3)*4;
  const int bgl = 64*bt + m;
  const int j0 = 16*jt + u0;
  const int kk8 = 8*(l >> 4);
  const int row0 = 64*bt + 32*mw + (l & 15);   // mt=0 batch row
  const int row1 = row0 + 16;                  // mt=1 batch row
  int bad = 0;                               // wave-0 poll timeout latch

  // prologue: x fragments for step 0 (gathered; bit-identical to xb path)
  short8 xf[2][5];                           // 40 VGPRs
  {
    int i0 = inputs[row0*128 + 0], i1 = inputs[row1*128 + 0];
    int d0 = dirs[row0*128 + 0],  d1 = dirs[row1*128 + 0];
#pragma unroll
    for (int ch = 0; ch < 4; ch++) {
      xf[0][ch] = *(const short8*)&linkb[(int64_t)i0*128 + 32*ch + kk8];
      xf[1][ch] = *(const short8*)&linkb[(int64_t)i1*128 + 32*ch + kk8];
    }
    xf[0][4] = *(const short8*)&direb[d0*32 + kk8];
    xf[1][4] = *(const short8*)&direb[d1*32 + kk8];
  }

  for (int s = 0; s < 128; s++) {
    const unsigned short* hp = (s & 1) ? hb1 : hb0;
    unsigned short* hn = (s & 1) ? hb0 : hb1;

    // ---- x-gates for step s (bit-exact with k_gatesx; no h dependency) ----
    uint2 gxr[2][2];
#pragma unroll
    for (int mt = 0; mt < 2; mt++)
#pragma unroll
    for (int nt = 0; nt < 2; nt++) {
      f32x4 a;
      a[0] = bias_b[nt]; a[1] = bias_b[nt]; a[2] = bias_b[nt]; a[3] = bias_b[nt];
#pragma unroll
      for (int ch = 0; ch < 5; ch++)
        a = MFMA(xf[mt][ch], Wx[ch][nt], a);
      unsigned short* ps = (unsigned short*)&gxr[mt][nt];
      ps[0] = f2bf(a[0]); ps[1] = f2bf(a[1]); ps[2] = f2bf(a[2]); ps[3] = f2bf(a[3]);
    }

    // ---- prefetch x fragments for step s+1 (plain cached gathers; tables
    // are read-only and L2-resident) ----
    {
      int sn = (s + 1 < 128) ? s + 1 : 127;
      int i0 = inputs[row0*128 + sn], i1 = inputs[row1*128 + sn];
      int d0 = dirs[row0*128 + sn],  d1 = dirs[row1*128 + sn];
#pragma unroll
      for (int ch = 0; ch < 4; ch++) {
        xf[0][ch] = *(const short8*)&linkb[(int64_t)i0*128 + 32*ch + kk8];
        xf[1][ch] = *(const short8*)&linkb[(int64_t)i1*128 + 32*ch + kk8];
      }
      xf[0][4] = *(const short8*)&direb[d0*32 + kk8];
      xf[1][4] = *(const short8*)&direb[d1*32 + kk8];
    }

    // ---- wait: all 32 group flags >= s (wave 0 polls; BOUNDED) ----
    if (s > 0) {
      if (w == 0 && !bad) {
        unsigned tgt = (unsigned)s;
        if (loc) {
          // L2 pair: sc0 tight poll matches the plain flag store (same
          // proven discipline as the h channel). No sleep: observation
          // latency ~ one L2 round trip.
          for (int it2 = 0; ; ++it2) {
            unsigned v;
            asm volatile("global_load_dword %0, %1, off sc0"
                         : "=v"(v) : "v"(&gf[l & 31]) : "memory");
            asm volatile("s_waitcnt vmcnt(0)" ::: "memory");
            if (__all((int)(v >= tgt))) break;
            if (it2 > 400000) { bad = 1; break; }  // terminate, don't hang
          }
        } else {
          for (int it2 = 0; ; ++it2) {
            unsigned v = __hip_atomic_load(&gf[l & 31], __ATOMIC_RELAXED,
                                           __HIP_MEMORY_SCOPE_AGENT);
            if (__all((int)(v >= tgt))) break;
            if (it2 > 400000) { bad = 1; break; }
            __builtin_amdgcn_s_sleep(1);
          }
        }
      }
      __syncthreads();
    }

    // ---- stage A tile (64 rows x K=512) -> LDS ----
    if (loc) {
      // h channel: plain stores landed dirty in this XCD's shared L2;
      // sc0-only batched loads read them (L1-bypass), fully pipelined.
      uint4 tmp[16];
#pragma unroll
      for (int i = 0; i < 16; i++) {
        int p = w*16 + i;                    // = ch*8 + ks*4 + ms
        int ms = p & 3, ks = (p >> 2) & 1, ch = p >> 3;
        int row = 64*bt + 16*ms + (l & 15);
        int k = 64*ch + 32*ks + 8*(l >> 4);
        const unsigned short* src = hp + (int64_t)row*512 + k;
        asm volatile("global_load_dwordx4 %0, %1, off sc0"
                     : "=v"(tmp[i]) : "v"(src) : "memory");
      }
      asm volatile("s_waitcnt vmcnt(0)" ::: "memory");
      __builtin_amdgcn_sched_barrier(0);
#pragma unroll
      for (int i = 0; i < 16; i++) {
        int p = w*16 + i;
        *(uint4*)&Ash[(p*64 + l)*8] = tmp[i];
      }
    } else {
      // agent-scope loads from the L3 coherence point (R7-proven)
#pragma unroll
      for (int i = 0; i < 16; i++) {
        int p = w*16 + i;
        int ms = p & 3, ks = (p >> 2) & 1, ch = p >> 3;
        int row = 64*bt + 16*ms + (l & 15);
        int k = 64*ch + 32*ks + 8*(l >> 4);
        const unsigned long long* src =
            (const unsigned long long*)(hp + (int64_t)row*512 + k);
        unsigned long long d0 = __hip_atomic_load(src,     __ATOMIC_RELAXED,
                                                  __HIP_MEMORY_SCOPE_AGENT);
        unsigned long long d1 = __hip_atomic_load(src + 1, __ATOMIC_RELAXED,
                                                  __HIP_MEMORY_SCOPE_AGENT);
        unsigned long long tmp2[2] = {d0, d1};
        *(uint4*)&Ash[(p*64 + l)*8] = *(const uint4*)tmp2;
      }
    }
    __syncthreads();

    f32x4 acc[2][2];
#pragma unroll
    for (int mt = 0; mt < 2; mt++)
#pragma unroll
    for (int nt = 0; nt < 2; nt++) {
      const unsigned short* pk = (const unsigned short*)&gxr[mt][nt];
      f32x4 v;
      v[0] = bf2f(pk[0]); v[1] = bf2f(pk[1]); v[2] = bf2f(pk[2]); v[3] = bf2f(pk[3]);
      acc[mt][nt] = v;
    }

#pragma unroll
    for (int ch = 0; ch < 8; ch++)
#pragma unroll
    for (int ks = 0; ks < 2; ks++) {
      short8 A0 = *(short8*)&Ash[((ch*8 + ks*4 + 2*mw + 0)*64 + l)*8];
      short8 A1 = *(short8*)&Ash[((ch*8 + ks*4 + 2*mw + 1)*64 + l)*8];
      acc[0][0] = MFMA(A0, Bw[ch][ks][0], acc[0][0]);
      acc[0][1] = MFMA(A0, Bw[ch][ks][1], acc[0][1]);
      acc[1][0] = MFMA(A1, Bw[ch][ks][0], acc[1][0]);
      acc[1][1] = MFMA(A1, Bw[ch][ks][1], acc[1][1]);
    }

    // gate exchange
#pragma unroll
    for (int mt = 0; mt < 2; mt++)
#pragma unroll
    for (int nt = 0; nt < 2; nt++) {
      int cb = 32*nw + 16*nt + (l & 15);
      int rb = 32*mw + 16*mt + (l >> 4)*4;
      f32x4 a = acc[mt][nt];
#pragma unroll
      for (int r = 0; r < 4; r++) gsh[rb + r][cb] = a[r];
    }
    __syncthreads();

    {
      union { unsigned short hs[4]; unsigned long long v; } hv;
#pragma unroll
      for (int i2 = 0; i2 < 4; i2++) {
        float gi = gsh[m][ 0 + u0 + i2];
        float gf2 = gsh[m][16 + u0 + i2];
        float gg = gsh[m][32 + u0 + i2];
        float go = gsh[m][48 + u0 + i2];
        float ii = 1.f/(1.f + expf(-gi));
        float ff = 1.f/(1.f + expf(-gf2));
        float g2 = tanhf(gg);
        float oo = 1.f/(1.f + expf(-go));
        float cv = ff*creg[i2] + ii*g2;
        creg[i2] = cv;
        hv.hs[i2] = f2bf(oo * tanhf(cv));
      }
      if (loc)   // plain store: dirty line in this XCD's L2 (exchange point)
        *(unsigned long long*)&hn[(int64_t)bgl*512 + j0] = hv.v;
      else       // agent store: write-through to the L3 coherence point
        __hip_atomic_store((unsigned long long*)&hn[(int64_t)bgl*512 + j0],
                           hv.v, __ATOMIC_RELAXED, __HIP_MEMORY_SCOPE_AGENT);
    }

    // __syncthreads drains vmcnt(0) in every wave (h stores ACKed at the
    // exchange point) BEFORE the flag post -> release without any fence.
    __syncthreads();
    if (t == 0) {
      asm volatile("s_waitcnt vmcnt(0)" ::: "memory");  // belt-and-braces
      unsigned fv = (unsigned)(s + 1);
      if (loc) {
        // plain store: dirties this XCD's L2 line, matching the sc0 poll
        asm volatile("global_store_dword %0, %1, off"
                     :: "v"(&gf[jt]), "v"(fv) : "memory");
      } else {
        __hip_atomic_store(&gf[jt], fv, __ATOMIC_RELAXED,
                           __HIP_MEMORY_SCOPE_AGENT);
      }
    }
  }
}

// ---------------- generic bf16 GEMM: C = act(A(MxK) * B(NxK)^T + bias) -----
// MODE 0: bf16 out + bias + relu;  MODE 1: f32 out + bias, cols < nreal;
// MODE 2: f32 out replicated x5 (pred_hard), row stride 40960.
template<int MODE>
__global__ __launch_bounds__(256) void k_gemm(
    const unsigned short* __restrict__ A, int lda,
    const unsigned short* __restrict__ Bm, int ldb, int nreal,
    const float* __restrict__ bias,
    void* __restrict__ outp, int ldo, int nchunks)
{
  const int bX = blockIdx.x, bY = blockIdx.y;
  const int t = threadIdx.x, w = t >> 6, l = t & 63;
  const int mw = w & 1, nw = w >> 1;
  __shared__ unsigned short Ash[4*2*64*8];
  __shared__ unsigned short Bsh[4*2*64*8];

  f32x4 acc[2][2];
  f32x4 z; z[0] = 0.f; z[1] = 0.f; z[2] = 0.f; z[3] = 0.f;
  acc[0][0] = z; acc[0][1] = z; acc[1][0] = z; acc[1][1] = z;

  for (int ch = 0; ch < nchunks; ch++) {
    __syncthreads();
#pragma unroll
    for (int i = 0; i < 2; i++) {
      int slot = t + 256*i;
      int p = slot >> 6, ll = slot & 63;
      int ms = p >> 1, ks = p & 1;
      int row = 64*bY + 16*ms + (ll & 15);
      int k = 64*ch + 32*ks + 8*(ll >> 4);
      *(uint4*)&Ash[slot*8] = *(const uint4*)&A[(int64_t)row*lda + k];
    }
#pragma unroll
    for (int i = 0; i < 2; i++) {
      int slot = t + 256*i;
      int p = slot >> 6, ll = slot & 63;
      int ns = p >> 1, ks = p & 1;
      int row = 64*bX + 16*ns + (ll & 15);
      if (row >= nreal) row = nreal - 1;   // clamp (garbage cols masked later)
      int k = 64*ch + 32*ks + 8*(ll >> 4);
      *(uint4*)&Bsh[slot*8] = *(const uint4*)&Bm[(int64_t)row*ldb + k];
    }
    __syncthreads();
#pragma unroll
    for (int ks = 0; ks < 2; ks++) {
      short8 A0 = *(short8*)&Ash[(((2*mw+0)*2 + ks)*64 + l)*8];
      short8 A1 = *(short8*)&Ash[(((2*mw+1)*2 + ks)*64 + l)*8];
      short8 B0 = *(short8*)&Bsh[(((2*nw+0)*2 + ks)*64 + l)*8];
      short8 B1 = *(short8*)&Bsh[(((2*nw+1)*2 + ks)*64 + l)*8];
      acc[0][0] = MFMA(A0, B0, acc[0][0]);
      acc[0][1] = MFMA(A0, B1, acc[0][1]);
      acc[1][0] = MFMA(A1, B0, acc[1][0]);
      acc[1][1] = MFMA(A1, B1, acc[1][1]);
    }
  }

#pragma unroll
  for (int mt = 0; mt < 2; mt++)
#pragma unroll
  for (int nt = 0; nt < 2; nt++) {
    int n = 64*bX + 32*nw + 16*nt + (l & 15);
    int rb = 64*bY + 32*mw + 16*mt + (l >> 4)*4;
    f32x4 a = acc[mt][nt];
    if (MODE == 0) {
      float bv = bias[n];
#pragma unroll
      for (int r = 0; r < 4; r++) {
        float v = a[r] + bv; v = v > 0.f ? v : 0.f;
        ((unsigned short*)outp)[(int64_t)(rb + r)*ldo + n] = f2bf(v);
      }
    } else if (MODE == 1) {
      if (n < nreal) {
        float bv = bias[n];
#pragma unroll
        for (int r = 0; r < 4; r++)
          ((float*)outp)[(int64_t)(rb + r)*ldo + n] = a[r] + bv;
      }
    } else {
#pragma unroll
      for (int r = 0; r < 4; r++) {
        float v = a[r];
        float* o = (float*)outp + (int64_t)(rb + r)*40960 + n;
#pragma unroll
        for (int p5 = 0; p5 < 5; p5++) o[p5*8192] = v;
      }
    }
  }
}

// ---------------- K4: softmax head, top-2, loss, count, query, pdr copy ----
__global__ __launch_bounds__(256) void k_head(
    const float* __restrict__ logits, const int* __restrict__ inputs,
    const int* __restrict__ goal, const int* __restrict__ ldm,
    const float* __restrict__ link, const float* __restrict__ dire,
    const float* __restrict__ pdr, unsigned short* __restrict__ qb,
    float* __restrict__ out)
{
  const int blk = blockIdx.x, t = threadIdx.x;
  __shared__ int idxsh[64][2];
  __shared__ float redf[256];
  __shared__ int redi[256];

  if (t < 64) {                       // top-2 for this block's 64 rows
    int b = 64*blk + t;
    float v[8];
#pragma unroll
    for (int i = 0; i < 8; i++) v[i] = logits[b*8 + i];
    int i0 = 0; float m0 = v[0];
#pragma unroll
    for (int i = 1; i < 8; i++) if (v[i] > m0) { m0 = v[i]; i0 = i; }
    int i1 = -1; float m1 = -3.4e38f;
#pragma unroll
    for (int i = 0; i < 8; i++) if (i != i0 && v[i] > m1) { m1 = v[i]; i1 = i; }
    idxsh[t][0] = i0; idxsh[t][1] = i1;
  }
  __syncthreads();
  {                                   // query = le + pad(0.5*(de0+de1)) (bf16)
    int rl = t >> 2, kc = (t & 3) * 32;
    int b = 64*blk + rl;
    int last = inputs[b*128 + 127];
    const float* le = link + (int64_t)last*128 + kc;
    int i0 = idxsh[rl][0], i1 = idxsh[rl][1];
    unsigned short q[32] __attribute__((aligned(16)));
#pragma unroll
    for (int k = 0; k < 32; k++) {
      float v = le[k];
      if (kc == 0) v += 0.5f*(dire[(i0+1)*32 + k] + dire[(i1+1)*32 + k]);
      q[k] = f2bf(v);
    }
    uint4* dst = (uint4*)&qb[b*128 + kc];
#pragma unroll
    for (int x = 0; x < 4; x++) dst[x] = ((uint4*)q)[x];
  }
  if (blk == 0) {                     // loss + direction_correct over all rows
    float lsum = 0.f; int csum = 0;
    for (int rr = t; rr < 512; rr += 256) {
      float v[8];
#pragma unroll
      for (int i = 0; i < 8; i++) v[i] = logits[rr*8 + i];
      float mx = v[0];
#pragma unroll
      for (int i = 1; i < 8; i++) mx = v[i] > mx ? v[i] : mx;
      float se = 0.f;
#pragma unroll
      for (int i = 0; i < 8; i++) se += expf(v[i] - mx);
      float lse = logf(se);
      int last = inputs[rr*128 + 127];
      int lbl = ldm[(int64_t)(last - 1)*8192 + goal[rr]];
      lsum += v[lbl] - mx - lse;      // ls2 == log_softmax (idempotent)
      int i0 = 0; float m0 = v[0];
#pragma unroll
      for (int i = 1; i < 8; i++) if (v[i] > m0) { m0 = v[i]; i0 = i; }
      int i1 = -1; float m1 = -3.4e38f;
#pragma unroll
      for (int i = 0; i < 8; i++) if (i != i0 && v[i] > m1) { m1 = v[i]; i1 = i; }
      if (i0 == lbl || i1 == lbl) csum++;
    }
    redf[t] = lsum; redi[t] = csum;
    __syncthreads();
    for (int o2 = 128; o2 > 0; o2 >>= 1) {
      if (t < o2) { redf[t] += redf[t + o2]; redi[t] += redi[t + o2]; }
      __syncthreads();
    }
    if (t == 0) {
      out[20992000] = -redf[0] / 512.f * 5.f;
      out[20992001] = (float)redi[0];
    }
  }
  for (int i = 0; i < 10; i++) {      // pred_d_rand passthrough
    int idx = blk*2560 + t*10 + i;
    out[20971520 + idx] = pdr[idx];
  }
}

// ---------------- host ----------------
extern "C" void kernel_launch(void* const* d_in, const int* in_sizes, int n_in,
                              void* d_out, int out_size, void* d_ws, size_t ws_size,
                              hipStream_t stream)
{
  const int* inputs = (const int*)d_in[0];
  const int* dirs   = (const int*)d_in[1];
  const int* goal   = (const int*)d_in[2];
  const int* ldm    = (const int*)d_in[3];
  const float* pdr  = (const float*)d_in[4];
  const float* link = (const float*)d_in[5];
  const float* dire = (const float*)d_in[6];
  const float* w_ih = (const float*)d_in[7];
  const float* b_ih = (const float*)d_in[8];
  const float* w_hh = (const float*)d_in[9];
  const float* b_hh = (const float*)d_in[10];
  const float* W1   = (const float*)d_in[11];
  const float* b1   = (const float*)d_in[12];
  const float* W2   = (const float*)d_in[13];
  const float* b2   = (const float*)d_in[14];
  const float* W3   = (const float*)d_in[15];
  const float* b3   = (const float*)d_in[16];
  float* out = (float*)d_out;

  char* wsp = (char*)d_ws;
  size_t off = 0;
  auto alloc = [&](size_t bytes) { char* p = wsp + off; off += (bytes + 255) & ~(size_t)255; return p; };
  unsigned short* xb    = (unsigned short*)alloc(10485760ull*2);  // fallback only
  unsigned short* wihb  = (unsigned short*)alloc(327680ull*2);
  unsigned short* whhb  = (unsigned short*)alloc(1048576ull*2);
  unsigned short* w1b   = (unsigned short*)alloc(262144ull*2);
  unsigned short* w2b   = (unsigned short*)alloc(262144ull*2);
  unsigned short* w3b   = (unsigned short*)alloc(4096ull*2);
  unsigned short* linkb = (unsigned short*)alloc(1048704ull*2);
  unsigned short* direb = (unsigned short*)alloc(288ull*2);
  float* bias_sum       = (float*)alloc(2048ull*4);
  unsigned short* gxb   = (unsigned short*)alloc(134217728ull*2);  // fallback only
  unsigned short* hb0   = (unsigned short*)alloc(262144ull*2);
  unsigned short* hb1   = (unsigned short*)alloc(262144ull*2);
  float* cbuf           = (float*)alloc(262144ull*4);
  unsigned short* z1b   = (unsigned short*)alloc(262144ull*2);
  unsigned short* z2b   = (unsigned short*)alloc(262144ull*2);
  float* logits         = (float*)alloc(4096ull*4);
  unsigned short* qb    = (unsigned short*)alloc(65536ull*2);
  unsigned int* flags   = (unsigned int*)alloc(4096);   // 8x64 u32 (256B/grp)
  unsigned int* cnt     = (unsigned int*)alloc(256);    // roster counters

  hipMemsetAsync(hb0, 0, 262144ull*2, stream);    // h0 = 0 (bf16 zeros)
  hipMemsetAsync(flags, 0, 4096, stream);         // flags = 0
  hipMemsetAsync(cnt, 0, 256, stream);            // roster counters = 0

  k_prep<<<11546, 256, 0, stream>>>(link, dire, w_ih, w_hh, W1, W2, W3,
                                    b_ih, b_hh, wihb, whhb, w1b, w2b, w3b,
                                    linkb, direb, bias_sum);

  {
    unsigned short* a0 = hb0; unsigned short* a1 = hb1;
    const unsigned short* a2 = whhb; const unsigned short* a3 = wihb;
    const int* a4 = inputs; const int* a5 = dirs;
    const unsigned short* a6 = linkb; const unsigned short* a7 = direb;
    const float* a8 = bias_sum;
    unsigned int* a9 = flags; unsigned int* a10 = cnt;
    void* kargs[11] = { &a0, &a1, &a2, &a3, &a4, &a5, &a6, &a7, &a8, &a9, &a10 };
    hipError_t ce = hipLaunchCooperativeKernel((const void*)k_lstm_all,
                                               dim3(256,1,1), dim3(256,1,1),
                                               kargs, 0, stream);
    if (ce != hipSuccess) {
      // fallback: materialize xb + gx then per-step launches (verified path)
      k_prep_xb<<<40960, 256, 0, stream>>>(inputs, dirs, link, dire, xb);
      k_gatesx<<<dim3(16,2,128), 256, 0, stream>>>(xb, wihb, bias_sum, gxb);
      hipMemsetAsync(cbuf, 0, 262144ull*4, stream);
      for (int s = 0; s < 128; s++) {
        const unsigned short* hp = (s & 1) ? hb1 : hb0;
        unsigned short* hn = (s & 1) ? hb0 : hb1;
        k_lstm_step<<<dim3(32,8), 256, 0, stream>>>(hp, hn, cbuf, whhb, gxb, s);
      }
    }
  }
  // final h in hb0 (128 steps, even)
  k_gemm<0><<<dim3(8,8), 256, 0, stream>>>(hb0, 512, w1b, 512, 512, b1, z1b, 512, 8);
  k_gemm<0><<<dim3(8,8), 256, 0, stream>>>(z1b, 512, w2b, 512, 512, b2, z2b, 512, 8);
  k_gemm<1><<<dim3(1,8), 256, 0, stream>>>(z2b, 512, w3b, 512, 8, b3, logits, 8, 8);
  k_head<<<8, 256, 0, stream>>>(logits, inputs, goal, ldm, link, dire, pdr, qb, out);
  k_gemm<2><<<dim3(128,8), 256, 0, stream>>>(qb, 128, linkb + 128, 128, 8192, nullptr, out, 0, 2);
}